// Round 11
// baseline (78.853 us; speedup 1.0000x reference)
//
#include <hip/hip_runtime.h>

#define NB   1024
#define NT   256
#define BTOT 262144   // NB*NT == B

typedef __attribute__((ext_vector_type(8))) short short8;
typedef __attribute__((ext_vector_type(4))) float f32x4;

__device__ __forceinline__ float relu_(float x) { return fmaxf(x, 0.0f); }

__device__ __forceinline__ short f2bf(float x) {   // RNE f32->bf16
    unsigned u = __float_as_uint(x);
    return (short)((u + 0x7FFFu + ((u >> 16) & 1u)) >> 16);
}
__device__ __forceinline__ unsigned pk2bf(float a, float b) {
    return ((unsigned)(unsigned short)f2bf(a)) |
           (((unsigned)(unsigned short)f2bf(b)) << 16);
}
__device__ __forceinline__ float bf2f(unsigned u16) {
    return __uint_as_float(u16 << 16);
}
__device__ __forceinline__ short8 pack8(float a0,float a1,float a2,float a3,
                                        float a4,float a5,float a6,float a7) {
    short8 r;
    r[0]=f2bf(a0); r[1]=f2bf(a1); r[2]=f2bf(a2); r[3]=f2bf(a3);
    r[4]=f2bf(a4); r[5]=f2bf(a5); r[6]=f2bf(a6); r[7]=f2bf(a7);
    return r;
}

// d_ws byte map:
//  0    : (reserved)            | A0 packed bf16 pairs at dword 160
//  768  : 46 B-fragments x 512 shorts (bf16), biases folded as extra K-rows:
//         B1: frag 0..3   (conv1, K=36 data + bias@36)
//         B2: frag 4..11  (conv2, K=40 data + bias@40)
//         B3: frag 12..19 (conv3, K=60 data + bias@60)
//         F1: frag 20..33 (fc1,   K=60 data + bias@60)
//         F2: frag 34..45 (fc2,   K=100 data + bias@100)
//  47872: partials [NB*12] f32
#define A0_DW    160
#define FRAGS_BYTE 768
#define PART_BYTE 47872
#define NFRAG 46

__global__ __launch_bounds__(256) void kp_setup(
    const float* __restrict__ w1, const float* __restrict__ b1,
    const float* __restrict__ g1, const float* __restrict__ bt1,
    const float* __restrict__ m1, const float* __restrict__ v1,
    const float* __restrict__ w2, const float* __restrict__ b2,
    const float* __restrict__ g2, const float* __restrict__ bt2,
    const float* __restrict__ m2, const float* __restrict__ v2,
    const float* __restrict__ w3, const float* __restrict__ b3,
    const float* __restrict__ g3, const float* __restrict__ bt3,
    const float* __restrict__ m3, const float* __restrict__ v3,
    const float* __restrict__ fw1, const float* __restrict__ fb1,
    const float* __restrict__ fw2, const float* __restrict__ fb2,
    float* __restrict__ wsB, short* __restrict__ frags)
{
    __shared__ float w1f[180], b1f[10], a0f[10];
    __shared__ float w2f[400], b2f[20];
    __shared__ float w3f[1200], b3f[30];
    const int t = threadIdx.x;

    if (t < 10) {
        float s = g1[t] * rsqrtf(v1[t] + 1e-5f);
        float bb = (b1[t] - m1[t]) * s + bt1[t];
        b1f[t] = bb; a0f[t] = relu_(bb);
        for (int i = 0; i < 18; ++i) w1f[t * 18 + i] = w1[t * 18 + i] * s;
    } else if (t >= 64 && t < 84) {
        int o = t - 64;
        float s = g2[o] * rsqrtf(v2[o] + 1e-5f);
        b2f[o] = (b2[o] - m2[o]) * s + bt2[o];
        for (int i = 0; i < 20; ++i) w2f[o * 20 + i] = w2[o * 20 + i] * s;
    } else if (t >= 128 && t < 158) {
        int o = t - 128;
        float s = g3[o] * rsqrtf(v3[o] + 1e-5f);
        b3f[o] = (b3[o] - m3[o]) * s + bt3[o];
        for (int i = 0; i < 40; ++i) w3f[o * 40 + i] = w3[o * 40 + i] * s;
    }
    __syncthreads();

    if (blockIdx.x == 0 && t < 5)
        ((unsigned*)wsB)[A0_DW + t] = pk2bf(a0f[2 * t], a0f[2 * t + 1]);

    for (int e = blockIdx.x * 256 + t; e < NFRAG * 512; e += gridDim.x * 256) {
        int frag = e >> 9, l = (e >> 3) & 63, j = e & 7;
        float val = 0.f;
        if (frag < 4) {                       // conv1: K=36 + bias@36, N=20
            int p = frag, nt = p >> 1, kt = p & 1;
            int k = kt * 32 + (l >> 4) * 8 + j, n = nt * 16 + (l & 15);
            if (n < 20) {
                int o = n % 10, pp = n / 10;
                if (k < 36) { int i = k >> 1, s = k & 1; if (s == pp) val = w1f[o * 18 + i]; }
                else if (k == 36) val = b1f[o];
            }
        } else if (frag < 12) {               // conv2: K=40 + bias@40, N=60
            int p = frag - 4, nt = p >> 1, kt = p & 1;
            int k = kt * 32 + (l >> 4) * 8 + j, n = nt * 16 + (l & 15);
            if (n < 60) {
                int q = n / 20, o = n % 20;
                if (k < 40) { int pp = k / 10, i = k % 10, d = pp - q;
                              if (d == 0 || d == 1) val = w2f[o * 20 + i * 2 + d]; }
                else if (k == 40) val = b2f[o];
            }
        } else if (frag < 20) {               // conv3: K=60 + bias@60, N=60
            int p = frag - 12, nt = p >> 1, kt = p & 1;
            int k = kt * 32 + (l >> 4) * 8 + j, n = nt * 16 + (l & 15);
            if (n < 60) {
                int q = n / 30, o = n % 30;
                if (k < 60) { int pp = k / 20, i = k % 20, d = pp - q;
                              if (d == 0 || d == 1) val = w3f[o * 40 + i * 2 + d]; }
                else if (k == 60) val = b3f[o];
            }
        } else if (frag < 34) {               // fc1: K=60 + bias@60, N=100
            int p = frag - 20, n7 = p >> 1, kt = p & 1;
            int k = kt * 32 + (l >> 4) * 8 + j, col = n7 * 16 + (l & 15);
            if (col < 100) {
                if (k < 60) val = fw1[col * 60 + k];
                else if (k == 60) val = fb1[col];
            }
        } else {                              // fc2: K=100 + bias@100, N=36
            int p = frag - 34, n3 = p >> 2, kt = p & 3;
            int k = kt * 32 + (l >> 4) * 8 + j, col = n3 * 16 + (l & 15);
            if (col < 36) {
                if (k < 100) val = fw2[col * 100 + k];
                else if (k == 100) val = fb2[col];
            }
        }
        frags[e] = f2bf(val);
    }
}

__global__ __launch_bounds__(NT) void kp_main(
    const float* __restrict__ cin, const int* __restrict__ tmask,
    const float* __restrict__ wsB, const short* __restrict__ frags,
    float* __restrict__ xout, float* __restrict__ missout,
    float* __restrict__ partials)
{
    // 40960 B total = exactly 4 blocks/CU
    __shared__ __align__(16) unsigned char sOUT[NT * 88];       // out rows, bf16
    __shared__ __align__(16) unsigned char sT1[4 * 16 * 144];   // a1 tiles (per-wave)
    __shared__ __align__(16) unsigned char sT2[4 * 16 * 144];   // a2/f/z tiles

    const int t = threadIdx.x;
    const int lane = t & 63, wave = t >> 6;
    const unsigned lrow = (unsigned)(lane & 15);
    const unsigned lkg  = (unsigned)(lane >> 4);
    const unsigned wbase = (unsigned)(t & ~63);
    const short8* frg = (const short8*)frags;

    const unsigned* a0p = (const unsigned*)wsB + A0_DW;
    uint4 A0q = *(const uint4*)a0p;
    unsigned A0e = a0p[4];

    unsigned char* T1 = sT1 + wave * (16 * 144);
    unsigned char* T2 = sT2 + wave * (16 * 144);

    // one-time: T1 col 40 = 1.0 (bias-one for conv2); pad cols are garbage-proof
    // (all B rows beyond logical K are zero)
    if (lane < 16)
        *(unsigned*)&T1[lane * 144 + 80] = 0x00003F80u;

    #pragma unroll 1
    for (int m = 0; m < 4; ++m) {
        const unsigned Rb = wbase + 16u * (unsigned)m;

        // ---- conv1 A-frags straight from global (no LDS staging) ----
        const float* crow = cin + (size_t)(blockIdx.x * NT + Rb + lrow) * 36;
        float4 qa = *(const float4*)(crow + 8 * lkg);
        float4 qb = *(const float4*)(crow + 8 * lkg + 4);
        float4 qc = *(const float4*)(crow + 32);
        short8 Aa = pack8(qa.x, qa.y, qa.z, qa.w, qb.x, qb.y, qb.z, qb.w);
        float sf = (lkg == 0u) ? 1.f : 0.f;
        short8 Ab = pack8(qc.x * sf, qc.y * sf, qc.z * sf, qc.w * sf, sf, 0.f, 0.f, 0.f);

        // T2 col 60 = 1.0 (bias-one for conv3/fc1), re-set each tile (z destroys it)
        if (lane < 16)
            *(unsigned*)&T2[lane * 144 + 120] = 0x00003F80u;

        // ---- conv1 -> a1 (T1 cols 10..29); bias folded ----
        {
            f32x4 D1[2];
            #pragma unroll
            for (int nt = 0; nt < 2; ++nt) {
                D1[nt] = (f32x4){0.f, 0.f, 0.f, 0.f};
                D1[nt] = __builtin_amdgcn_mfma_f32_16x16x32_bf16(Aa, frg[(nt * 2 + 0) * 64 + lane], D1[nt], 0, 0, 0);
                D1[nt] = __builtin_amdgcn_mfma_f32_16x16x32_bf16(Ab, frg[(nt * 2 + 1) * 64 + lane], D1[nt], 0, 0, 0);
            }
            #pragma unroll
            for (int nt = 0; nt < 2; ++nt) {
                int n1 = nt * 16 + (int)lrow;
                if (n1 < 20) {
                    #pragma unroll
                    for (int i = 0; i < 4; ++i)
                        *(short*)&T1[(4 * lkg + i) * 144 + (n1 + 10) * 2] =
                            f2bf(relu_(D1[nt][i]));
                }
            }
        }
        // A0 constants: cols 0..9 (pos0) and 30..39 (pos3)
        if (lane < 16) {
            unsigned char* b = &T1[(unsigned)lane * 144];
            *(uint4*)(b + 0) = A0q;
            *(unsigned*)(b + 16) = A0e;
        } else if (lane < 32) {
            unsigned char* b = &T1[(unsigned)(lane - 16) * 144];
            *(unsigned*)(b + 60) = A0q.x;
            *(uint4*)(b + 64) = make_uint4(A0q.y, A0q.z, A0q.w, A0e);
        }

        // ---- conv2: A = a1 (K=41) -> a2 (T2 cols 0..59) ----
        Aa = *(const short8*)&T1[lrow * 144 + lkg * 16u];
        Ab = *(const short8*)&T1[lrow * 144 + 64u + lkg * 16u];
        {
            f32x4 D2[4];
            #pragma unroll
            for (int nt = 0; nt < 4; ++nt) {
                D2[nt] = (f32x4){0.f, 0.f, 0.f, 0.f};
                D2[nt] = __builtin_amdgcn_mfma_f32_16x16x32_bf16(Aa, frg[(4 + nt * 2 + 0) * 64 + lane], D2[nt], 0, 0, 0);
                D2[nt] = __builtin_amdgcn_mfma_f32_16x16x32_bf16(Ab, frg[(4 + nt * 2 + 1) * 64 + lane], D2[nt], 0, 0, 0);
            }
            #pragma unroll
            for (int nt = 0; nt < 4; ++nt) {
                int n2 = nt * 16 + (int)lrow;
                if (n2 < 60) {
                    #pragma unroll
                    for (int i = 0; i < 4; ++i)
                        *(short*)&T2[(4 * lkg + i) * 144 + n2 * 2] =
                            f2bf(relu_(D2[nt][i]));
                }
            }
        }

        // ---- conv3: A = a2 (K=61) -> f (T2, kf = 2*(n%30)+n/30) ----
        Aa = *(const short8*)&T2[lrow * 144 + lkg * 16u];
        Ab = *(const short8*)&T2[lrow * 144 + 64u + lkg * 16u];
        {
            f32x4 D3[4];
            #pragma unroll
            for (int nt = 0; nt < 4; ++nt) {
                D3[nt] = (f32x4){0.f, 0.f, 0.f, 0.f};
                D3[nt] = __builtin_amdgcn_mfma_f32_16x16x32_bf16(Aa, frg[(12 + nt * 2 + 0) * 64 + lane], D3[nt], 0, 0, 0);
                D3[nt] = __builtin_amdgcn_mfma_f32_16x16x32_bf16(Ab, frg[(12 + nt * 2 + 1) * 64 + lane], D3[nt], 0, 0, 0);
            }
            #pragma unroll
            for (int nt = 0; nt < 4; ++nt) {
                int n3 = nt * 16 + (int)lrow;
                if (n3 < 60) {
                    int o = (n3 >= 30) ? n3 - 30 : n3;
                    int kf = 2 * o + (n3 >= 30 ? 1 : 0);
                    #pragma unroll
                    for (int i = 0; i < 4; ++i)
                        *(short*)&T2[(4 * lkg + i) * 144 + kf * 2] =
                            f2bf(relu_(D3[nt][i]));
                }
            }
        }

        // ---- fc1 + fc2 (A = f, K=61; z K=101 with z[100]=1) ----
        short8 Fa = *(const short8*)&T2[lrow * 144 + lkg * 16u];
        short8 Fb = *(const short8*)&T2[lrow * 144 + 64u + lkg * 16u];
        f32x4 acc2[3];
        #pragma unroll
        for (int n = 0; n < 3; ++n) acc2[n] = (f32x4){0.f, 0.f, 0.f, 0.f};

        #pragma unroll
        for (int h = 0; h < 2; ++h) {
            f32x4 acc1[4];
            #pragma unroll
            for (int nn = 0; nn < 4; ++nn) {
                const int n = 4 * h + nn;
                acc1[nn] = (f32x4){0.f, 0.f, 0.f, 0.f};
                if (n < 7) {
                    acc1[nn] = __builtin_amdgcn_mfma_f32_16x16x32_bf16(Fa, frg[(20 + n * 2 + 0) * 64 + lane], acc1[nn], 0, 0, 0);
                    acc1[nn] = __builtin_amdgcn_mfma_f32_16x16x32_bf16(Fb, frg[(20 + n * 2 + 1) * 64 + lane], acc1[nn], 0, 0, 0);
                }
            }
            #pragma unroll
            for (int nn = 0; nn < 4; ++nn) {
                const int n = 4 * h + nn;
                #pragma unroll
                for (int i = 0; i < 4; ++i) {
                    float zv = (n < 7) ? relu_(acc1[nn][i]) : 0.f;
                    if (n == 6 && (int)lrow == 4) zv = 1.f;   // z[100] = bias-one
                    *(short*)&T2[(4 * lkg + i) * 144 + (16 * nn + (int)lrow) * 2] = f2bf(zv);
                }
            }
            #pragma unroll
            for (int q = 0; q < 2; ++q) {
                const int kt = 2 * h + q;
                short8 Az = *(const short8*)&T2[lrow * 144 + (unsigned)(q * 64) + lkg * 16u];
                #pragma unroll
                for (int n = 0; n < 3; ++n)
                    acc2[n] = __builtin_amdgcn_mfma_f32_16x16x32_bf16(Az, frg[(34 + n * 4 + kt) * 64 + lane], acc2[n], 0, 0, 0);
            }
        }

        // out (bf16) -> sOUT rows of this tile (bias already in acc2)
        #pragma unroll
        for (int n = 0; n < 3; ++n) {
            const int col = 16 * n + (int)lrow;
            if (col < 36) {
                #pragma unroll
                for (int i = 0; i < 4; ++i)
                    *(short*)&sOUT[(Rb + 4 * lkg + i) * 88 + col * 2] =
                        f2bf(acc2[n][i]);
            }
        }
    }

    // ---- per-sample part losses: own out-row (bf16) + c reload (L2-hot) ----
    const float* cp = cin + (size_t)(blockIdx.x * NT + t) * 36;
    float cg[32];
    #pragma unroll
    for (int i = 0; i < 8; ++i)
        *(float4*)(cg + 4 * i) = *(const float4*)(cp + 4 * i);

    float o[32];
    #pragma unroll
    for (int j = 0; j < 8; ++j) {
        uint2 w = *(const uint2*)&sOUT[t * 88 + 8 * j];
        o[4 * j + 0] = __uint_as_float(w.x << 16);
        o[4 * j + 1] = __uint_as_float(w.x & 0xFFFF0000u);
        o[4 * j + 2] = __uint_as_float(w.y << 16);
        o[4 * j + 3] = __uint_as_float(w.y & 0xFFFF0000u);
    }

    float sp[5], np[5];
    {   // head (0,14,15); gt mixes x[:,15,0] and c[:,15,1] (faithful)
        float dxa = o[0] - o[28], dya = o[1] - o[29];
        float dxb = o[0] - o[30], dyb = o[1] - o[31];
        float pred = 0.5f * (sqrtf(dxa*dxa + dya*dya) + sqrtf(dxb*dxb + dyb*dyb));
        float cxa = cg[0] - cg[28], cya = cg[1] - cg[29];
        float gxa = cg[0] - o[30],  gya = cg[1] - cg[31];
        float gt = 0.5f * (sqrtf(cxa*cxa + cya*cya) + sqrtf(gxa*gxa + gya*gya));
        float vf = (cg[0] != -1.f && cg[28] != -1.f && cg[30] != -1.f) ? 1.f : 0.f;
        float e = pred - gt;
        sp[0] = e * e * vf; np[0] = vf;
    }
    #pragma unroll
    for (int p = 0; p < 4; ++p) {
        const int a = 2 + 3 * p, b = a + 1, cc = a + 2;
        float dxa = o[2*a] - o[2*b],  dya = o[2*a+1] - o[2*b+1];
        float dxb = o[2*b] - o[2*cc], dyb = o[2*b+1] - o[2*cc+1];
        float pred = 0.5f * (sqrtf(dxa*dxa + dya*dya) + sqrtf(dxb*dxb + dyb*dyb));
        float cxa = cg[2*a] - cg[2*b], cya = cg[2*a+1] - cg[2*b+1];
        float gxa = cg[2*b] - o[2*cc], gya = cg[2*b+1] - cg[2*cc+1];
        float gt = 0.5f * (sqrtf(cxa*cxa + cya*cya) + sqrtf(gxa*gxa + gya*gya));
        float vf = (cg[2*a] != -1.f && cg[2*b] != -1.f && cg[2*cc] != -1.f) ? 1.f : 0.f;
        float e = pred - gt;
        sp[p + 1] = e * e * vf; np[p + 1] = vf;
    }

    __syncthreads();   // all waves' out-rows complete

    // ---- coalesced x store + miss store + elementwise kp-loss ----
    const size_t blkBase = (size_t)blockIdx.x * (NT * 36);
    const float4* cin4 = (const float4*)(cin + blkBase);
    const int4*   tm4  = (const int4*)(tmask + blkBase);
    float4*       x4   = (float4*)(xout + blkBase);
    float*        mo   = missout + blkBase;

    float s1 = 0.f, s2 = 0.f;
    #pragma unroll
    for (int i = 0; i < 9; ++i) {
        int g4 = i * NT + t;
        unsigned g = 4u * (unsigned)g4;
        unsigned row = g / 36u;
        unsigned col = g - row * 36u;          // col % 4 == 0 -> 8B aligned
        uint2 w = *(const uint2*)&sOUT[row * 88u + col * 2u];
        float4 xv;
        xv.x = __uint_as_float(w.x << 16);
        xv.y = __uint_as_float(w.x & 0xFFFF0000u);
        xv.z = __uint_as_float(w.y << 16);
        xv.w = __uint_as_float(w.y & 0xFFFF0000u);
        float4 cv = cin4[g4];
        int4   mv = tm4[g4];
        x4[g4] = xv;
        mo[g + 0] = (cv.x != -1.f) ? 1.f : 0.f;
        mo[g + 1] = (cv.y != -1.f) ? 1.f : 0.f;
        mo[g + 2] = (cv.z != -1.f) ? 1.f : 0.f;
        mo[g + 3] = (cv.w != -1.f) ? 1.f : 0.f;
        float m0 = (float)mv.x, m1_ = (float)mv.y, m2_ = (float)mv.z, m3_ = (float)mv.w;
        float d0 = xv.x - cv.x, d1 = xv.y - cv.y, d2 = xv.z - cv.z, d3 = xv.w - cv.w;
        s1 += d0*d0*m0 + d1*d1*m1_ + d2*d2*m2_ + d3*d3*m3_;
        s2 += m0 + m1_ + m2_ + m3_;
    }

    // ---- block reduction of 12 scalars (scratch = dead sT1 region) ----
    float rv[12] = { s1, s2, sp[0], np[0], sp[1], np[1],
                     sp[2], np[2], sp[3], np[3], sp[4], np[4] };
    #pragma unroll
    for (int v = 0; v < 12; ++v) {
        #pragma unroll
        for (int off = 32; off > 0; off >>= 1)
            rv[v] += __shfl_down(rv[v], off, 64);
    }
    if (lane == 0) {
        float* sw = (float*)(sT1 + wave * (16 * 144));
        #pragma unroll
        for (int v = 0; v < 12; ++v) sw[v] = rv[v];
    }
    __syncthreads();
    if (t < 12) {
        float s = 0.f;
        #pragma unroll
        for (int w = 0; w < 4; ++w) s += ((const float*)(sT1 + w * (16 * 144)))[t];
        partials[blockIdx.x * 12 + t] = s;
    }
}

__global__ __launch_bounds__(256) void kp_fin(const float* __restrict__ partials,
                                              float* __restrict__ total_out)
{
    __shared__ float sred[4][12];
    const int t = threadIdx.x;
    float rv[12];
    #pragma unroll
    for (int v = 0; v < 12; ++v) rv[v] = 0.f;
    for (int b = t; b < NB; b += 256) {
        #pragma unroll
        for (int v = 0; v < 12; ++v) rv[v] += partials[b * 12 + v];
    }
    #pragma unroll
    for (int v = 0; v < 12; ++v) {
        #pragma unroll
        for (int off = 32; off > 0; off >>= 1)
            rv[v] += __shfl_down(rv[v], off, 64);
    }
    const int wave = t >> 6, lane = t & 63;
    if (lane == 0) {
        #pragma unroll
        for (int v = 0; v < 12; ++v) sred[wave][v] = rv[v];
    }
    __syncthreads();
    if (t == 0) {
        float acc[12];
        #pragma unroll
        for (int v = 0; v < 12; ++v)
            acc[v] = sred[0][v] + sred[1][v] + sred[2][v] + sred[3][v];
        float total = acc[0] / acc[1];
        #pragma unroll
        for (int p = 0; p < 5; ++p) {
            float s = acc[2 + 2 * p], n = acc[3 + 2 * p];
            total += (n > 0.f) ? (s / fmaxf(n, 1.f)) : 0.f;
        }
        total_out[0] = total;
    }
}

extern "C" void kernel_launch(void* const* d_in, const int* in_sizes, int n_in,
                              void* d_out, int out_size, void* d_ws, size_t ws_size,
                              hipStream_t stream)
{
    const float* cin   = (const float*)d_in[0];
    const int*   tmask = (const int*)  d_in[1];
    const float* w1  = (const float*)d_in[2];
    const float* b1  = (const float*)d_in[3];
    const float* g1  = (const float*)d_in[4];
    const float* bt1 = (const float*)d_in[5];
    const float* m1  = (const float*)d_in[6];
    const float* v1  = (const float*)d_in[7];
    const float* w2  = (const float*)d_in[8];
    const float* b2  = (const float*)d_in[9];
    const float* g2  = (const float*)d_in[10];
    const float* bt2 = (const float*)d_in[11];
    const float* m2  = (const float*)d_in[12];
    const float* v2  = (const float*)d_in[13];
    const float* w3  = (const float*)d_in[14];
    const float* b3  = (const float*)d_in[15];
    const float* g3  = (const float*)d_in[16];
    const float* bt3 = (const float*)d_in[17];
    const float* m3  = (const float*)d_in[18];
    const float* v3  = (const float*)d_in[19];
    const float* fw1 = (const float*)d_in[20];
    const float* fb1 = (const float*)d_in[21];
    const float* fw2 = (const float*)d_in[22];
    const float* fb2 = (const float*)d_in[23];

    float* xout     = (float*)d_out;                       // [B,36]
    float* total    = (float*)d_out + (size_t)BTOT * 36;   // scalar
    float* missout  = total + 1;                           // [B,36] as f32 0/1

    float* wsB      = (float*)d_ws;
    short* frags    = (short*)((char*)d_ws + FRAGS_BYTE);
    float* partials = (float*)((char*)d_ws + PART_BYTE);   // [NB,12]

    kp_setup<<<8, 256, 0, stream>>>(
        w1, b1, g1, bt1, m1, v1,
        w2, b2, g2, bt2, m2, v2,
        w3, b3, g3, bt3, m3, v3,
        fw1, fb1, fw2, fb2, wsB, frags);

    kp_main<<<NB, NT, 0, stream>>>(cin, tmask, wsB, frags,
        xout, missout, partials);

    kp_fin<<<1, 256, 0, stream>>>(partials, total);
}

// Round 12
// 78.611 us; speedup vs baseline: 1.0031x; 1.0031x over previous
//
#include <hip/hip_runtime.h>

#define NB   1024
#define NT   256
#define BTOT 262144   // NB*NT == B

typedef __attribute__((ext_vector_type(8))) short short8;
typedef __attribute__((ext_vector_type(4))) float f32x4;

__device__ __forceinline__ float relu_(float x) { return fmaxf(x, 0.0f); }

__device__ __forceinline__ short f2bf(float x) {   // RNE f32->bf16
    unsigned u = __float_as_uint(x);
    return (short)((u + 0x7FFFu + ((u >> 16) & 1u)) >> 16);
}
__device__ __forceinline__ unsigned pk2bf(float a, float b) {
    return ((unsigned)(unsigned short)f2bf(a)) |
           (((unsigned)(unsigned short)f2bf(b)) << 16);
}
__device__ __forceinline__ short8 pack8(float a0,float a1,float a2,float a3,
                                        float a4,float a5,float a6,float a7) {
    short8 r;
    r[0]=f2bf(a0); r[1]=f2bf(a1); r[2]=f2bf(a2); r[3]=f2bf(a3);
    r[4]=f2bf(a4); r[5]=f2bf(a5); r[6]=f2bf(a6); r[7]=f2bf(a7);
    return r;
}

// d_ws byte map:
//  0    : (reserved)            | A0 packed bf16 pairs at dword 160
//  768  : 46 B-fragments x 512 shorts (bf16), biases folded as extra K-rows
//  47872: partials [NB*12] f32
#define A0_DW    160
#define FRAGS_BYTE 768
#define PART_BYTE 47872
#define NFRAG 46

__global__ __launch_bounds__(256) void kp_setup(
    const float* __restrict__ w1, const float* __restrict__ b1,
    const float* __restrict__ g1, const float* __restrict__ bt1,
    const float* __restrict__ m1, const float* __restrict__ v1,
    const float* __restrict__ w2, const float* __restrict__ b2,
    const float* __restrict__ g2, const float* __restrict__ bt2,
    const float* __restrict__ m2, const float* __restrict__ v2,
    const float* __restrict__ w3, const float* __restrict__ b3,
    const float* __restrict__ g3, const float* __restrict__ bt3,
    const float* __restrict__ m3, const float* __restrict__ v3,
    const float* __restrict__ fw1, const float* __restrict__ fb1,
    const float* __restrict__ fw2, const float* __restrict__ fb2,
    float* __restrict__ wsB, short* __restrict__ frags)
{
    __shared__ float w1f[180], b1f[10], a0f[10];
    __shared__ float w2f[400], b2f[20];
    __shared__ float w3f[1200], b3f[30];
    const int t = threadIdx.x;

    if (t < 10) {
        float s = g1[t] * rsqrtf(v1[t] + 1e-5f);
        float bb = (b1[t] - m1[t]) * s + bt1[t];
        b1f[t] = bb; a0f[t] = relu_(bb);
        for (int i = 0; i < 18; ++i) w1f[t * 18 + i] = w1[t * 18 + i] * s;
    } else if (t >= 64 && t < 84) {
        int o = t - 64;
        float s = g2[o] * rsqrtf(v2[o] + 1e-5f);
        b2f[o] = (b2[o] - m2[o]) * s + bt2[o];
        for (int i = 0; i < 20; ++i) w2f[o * 20 + i] = w2[o * 20 + i] * s;
    } else if (t >= 128 && t < 158) {
        int o = t - 128;
        float s = g3[o] * rsqrtf(v3[o] + 1e-5f);
        b3f[o] = (b3[o] - m3[o]) * s + bt3[o];
        for (int i = 0; i < 40; ++i) w3f[o * 40 + i] = w3[o * 40 + i] * s;
    }
    __syncthreads();

    if (blockIdx.x == 0 && t < 5)
        ((unsigned*)wsB)[A0_DW + t] = pk2bf(a0f[2 * t], a0f[2 * t + 1]);

    for (int e = blockIdx.x * 256 + t; e < NFRAG * 512; e += gridDim.x * 256) {
        int frag = e >> 9, l = (e >> 3) & 63, j = e & 7;
        float val = 0.f;
        if (frag < 4) {                       // conv1: K=36 + bias@36, N=20
            int p = frag, nt = p >> 1, kt = p & 1;
            int k = kt * 32 + (l >> 4) * 8 + j, n = nt * 16 + (l & 15);
            if (n < 20) {
                int o = n % 10, pp = n / 10;
                if (k < 36) { int i = k >> 1, s = k & 1; if (s == pp) val = w1f[o * 18 + i]; }
                else if (k == 36) val = b1f[o];
            }
        } else if (frag < 12) {               // conv2: K=40 + bias@40, N=60
            int p = frag - 4, nt = p >> 1, kt = p & 1;
            int k = kt * 32 + (l >> 4) * 8 + j, n = nt * 16 + (l & 15);
            if (n < 60) {
                int q = n / 20, o = n % 20;
                if (k < 40) { int pp = k / 10, i = k % 10, d = pp - q;
                              if (d == 0 || d == 1) val = w2f[o * 20 + i * 2 + d]; }
                else if (k == 40) val = b2f[o];
            }
        } else if (frag < 20) {               // conv3: K=60 + bias@60, N=60
            int p = frag - 12, nt = p >> 1, kt = p & 1;
            int k = kt * 32 + (l >> 4) * 8 + j, n = nt * 16 + (l & 15);
            if (n < 60) {
                int q = n / 30, o = n % 30;
                if (k < 60) { int pp = k / 20, i = k % 20, d = pp - q;
                              if (d == 0 || d == 1) val = w3f[o * 40 + i * 2 + d]; }
                else if (k == 60) val = b3f[o];
            }
        } else if (frag < 34) {               // fc1: K=60 + bias@60, N=100
            int p = frag - 20, n7 = p >> 1, kt = p & 1;
            int k = kt * 32 + (l >> 4) * 8 + j, col = n7 * 16 + (l & 15);
            if (col < 100) {
                if (k < 60) val = fw1[col * 60 + k];
                else if (k == 60) val = fb1[col];
            }
        } else {                              // fc2: K=100 + bias@100, N=36
            int p = frag - 34, n3 = p >> 2, kt = p & 3;
            int k = kt * 32 + (l >> 4) * 8 + j, col = n3 * 16 + (l & 15);
            if (col < 36) {
                if (k < 100) val = fw2[col * 100 + k];
                else if (k == 100) val = fb2[col];
            }
        }
        frags[e] = f2bf(val);
    }
}

__global__ __launch_bounds__(NT) void kp_main(
    const float* __restrict__ cin, const int* __restrict__ tmask,
    const float* __restrict__ wsB, const short* __restrict__ frags,
    float* __restrict__ xout, float* __restrict__ missout,
    float* __restrict__ partials)
{
    // 40960 B total = exactly 4 blocks/CU
    __shared__ __align__(16) unsigned char sOUT[NT * 88];       // out rows, bf16
    __shared__ __align__(16) unsigned char sT1[4 * 16 * 144];   // a1 tiles (per-wave)
    __shared__ __align__(16) unsigned char sT2[4 * 16 * 144];   // a2/f/z tiles

    const int t = threadIdx.x;
    const int lane = t & 63, wave = t >> 6;
    const unsigned lrow = (unsigned)(lane & 15);
    const unsigned lkg  = (unsigned)(lane >> 4);
    const unsigned wbase = (unsigned)(t & ~63);
    const short8* frg = (const short8*)frags;

    const unsigned* a0p = (const unsigned*)wsB + A0_DW;
    uint4 A0q = *(const uint4*)a0p;
    unsigned A0e = a0p[4];

    unsigned char* T1 = sT1 + wave * (16 * 144);
    unsigned char* T2 = sT2 + wave * (16 * 144);

    // one-time: T1 col 40 = 1.0 (bias-one for conv2)
    if (lane < 16)
        *(unsigned*)&T1[lane * 144 + 80] = 0x00003F80u;

    #pragma unroll 1
    for (int m = 0; m < 4; ++m) {
        const unsigned Rb = wbase + 16u * (unsigned)m;

        // ---- conv1 A-frags straight from global ----
        const float* crow = cin + (size_t)(blockIdx.x * NT + Rb + lrow) * 36;
        float4 qa = *(const float4*)(crow + 8 * lkg);
        float4 qb = *(const float4*)(crow + 8 * lkg + 4);
        float4 qc = *(const float4*)(crow + 32);
        short8 Aa = pack8(qa.x, qa.y, qa.z, qa.w, qb.x, qb.y, qb.z, qb.w);
        float sf = (lkg == 0u) ? 1.f : 0.f;
        short8 Ab = pack8(qc.x * sf, qc.y * sf, qc.z * sf, qc.w * sf, sf, 0.f, 0.f, 0.f);

        // T2 col 60 = 1.0 (bias-one for conv3/fc1), re-set each tile
        if (lane < 16)
            *(unsigned*)&T2[lane * 144 + 120] = 0x00003F80u;

        // ---- conv1 -> a1 (T1 cols 10..29) ----
        {
            f32x4 D1[2];
            #pragma unroll
            for (int nt = 0; nt < 2; ++nt) {
                D1[nt] = (f32x4){0.f, 0.f, 0.f, 0.f};
                D1[nt] = __builtin_amdgcn_mfma_f32_16x16x32_bf16(Aa, frg[(nt * 2 + 0) * 64 + lane], D1[nt], 0, 0, 0);
                D1[nt] = __builtin_amdgcn_mfma_f32_16x16x32_bf16(Ab, frg[(nt * 2 + 1) * 64 + lane], D1[nt], 0, 0, 0);
            }
            #pragma unroll
            for (int nt = 0; nt < 2; ++nt) {
                int n1 = nt * 16 + (int)lrow;
                if (n1 < 20) {
                    #pragma unroll
                    for (int i = 0; i < 4; ++i)
                        *(short*)&T1[(4 * lkg + i) * 144 + (n1 + 10) * 2] =
                            f2bf(relu_(D1[nt][i]));
                }
            }
        }
        // A0 constants: cols 0..9 (pos0) and 30..39 (pos3)
        if (lane < 16) {
            unsigned char* b = &T1[(unsigned)lane * 144];
            *(uint4*)(b + 0) = A0q;
            *(unsigned*)(b + 16) = A0e;
        } else if (lane < 32) {
            unsigned char* b = &T1[(unsigned)(lane - 16) * 144];
            *(unsigned*)(b + 60) = A0q.x;
            *(uint4*)(b + 64) = make_uint4(A0q.y, A0q.z, A0q.w, A0e);
        }

        // ---- conv2: A = a1 (K=41) -> a2 (T2 cols 0..59) ----
        Aa = *(const short8*)&T1[lrow * 144 + lkg * 16u];
        Ab = *(const short8*)&T1[lrow * 144 + 64u + lkg * 16u];
        {
            f32x4 D2[4];
            #pragma unroll
            for (int nt = 0; nt < 4; ++nt) {
                D2[nt] = (f32x4){0.f, 0.f, 0.f, 0.f};
                D2[nt] = __builtin_amdgcn_mfma_f32_16x16x32_bf16(Aa, frg[(4 + nt * 2 + 0) * 64 + lane], D2[nt], 0, 0, 0);
                D2[nt] = __builtin_amdgcn_mfma_f32_16x16x32_bf16(Ab, frg[(4 + nt * 2 + 1) * 64 + lane], D2[nt], 0, 0, 0);
            }
            #pragma unroll
            for (int nt = 0; nt < 4; ++nt) {
                int n2 = nt * 16 + (int)lrow;
                if (n2 < 60) {
                    #pragma unroll
                    for (int i = 0; i < 4; ++i)
                        *(short*)&T2[(4 * lkg + i) * 144 + n2 * 2] =
                            f2bf(relu_(D2[nt][i]));
                }
            }
        }

        // ---- conv3: A = a2 (K=61) -> f (T2, kf = 2*(n%30)+n/30) ----
        Aa = *(const short8*)&T2[lrow * 144 + lkg * 16u];
        Ab = *(const short8*)&T2[lrow * 144 + 64u + lkg * 16u];
        {
            f32x4 D3[4];
            #pragma unroll
            for (int nt = 0; nt < 4; ++nt) {
                D3[nt] = (f32x4){0.f, 0.f, 0.f, 0.f};
                D3[nt] = __builtin_amdgcn_mfma_f32_16x16x32_bf16(Aa, frg[(12 + nt * 2 + 0) * 64 + lane], D3[nt], 0, 0, 0);
                D3[nt] = __builtin_amdgcn_mfma_f32_16x16x32_bf16(Ab, frg[(12 + nt * 2 + 1) * 64 + lane], D3[nt], 0, 0, 0);
            }
            #pragma unroll
            for (int nt = 0; nt < 4; ++nt) {
                int n3 = nt * 16 + (int)lrow;
                if (n3 < 60) {
                    int o = (n3 >= 30) ? n3 - 30 : n3;
                    int kf = 2 * o + (n3 >= 30 ? 1 : 0);
                    #pragma unroll
                    for (int i = 0; i < 4; ++i)
                        *(short*)&T2[(4 * lkg + i) * 144 + kf * 2] =
                            f2bf(relu_(D3[nt][i]));
                }
            }
        }

        // ---- fc1 + fc2 (A = f, K=61; z K=101 with z[100]=1) ----
        short8 Fa = *(const short8*)&T2[lrow * 144 + lkg * 16u];
        short8 Fb = *(const short8*)&T2[lrow * 144 + 64u + lkg * 16u];
        f32x4 acc2[3];
        #pragma unroll
        for (int n = 0; n < 3; ++n) acc2[n] = (f32x4){0.f, 0.f, 0.f, 0.f};

        #pragma unroll
        for (int h = 0; h < 2; ++h) {
            f32x4 acc1[4];
            #pragma unroll
            for (int nn = 0; nn < 4; ++nn) {
                const int n = 4 * h + nn;
                acc1[nn] = (f32x4){0.f, 0.f, 0.f, 0.f};
                if (n < 7) {
                    acc1[nn] = __builtin_amdgcn_mfma_f32_16x16x32_bf16(Fa, frg[(20 + n * 2 + 0) * 64 + lane], acc1[nn], 0, 0, 0);
                    acc1[nn] = __builtin_amdgcn_mfma_f32_16x16x32_bf16(Fb, frg[(20 + n * 2 + 1) * 64 + lane], acc1[nn], 0, 0, 0);
                }
            }
            #pragma unroll
            for (int nn = 0; nn < 4; ++nn) {
                const int n = 4 * h + nn;
                #pragma unroll
                for (int i = 0; i < 4; ++i) {
                    float zv = (n < 7) ? relu_(acc1[nn][i]) : 0.f;
                    if (n == 6 && (int)lrow == 4) zv = 1.f;   // z[100] = bias-one
                    *(short*)&T2[(4 * lkg + i) * 144 + (16 * nn + (int)lrow) * 2] = f2bf(zv);
                }
            }
            #pragma unroll
            for (int q = 0; q < 2; ++q) {
                const int kt = 2 * h + q;
                short8 Az = *(const short8*)&T2[lrow * 144 + (unsigned)(q * 64) + lkg * 16u];
                #pragma unroll
                for (int n = 0; n < 3; ++n)
                    acc2[n] = __builtin_amdgcn_mfma_f32_16x16x32_bf16(Az, frg[(34 + n * 4 + kt) * 64 + lane], acc2[n], 0, 0, 0);
            }
        }

        // out (bf16) -> sOUT rows of this tile
        #pragma unroll
        for (int n = 0; n < 3; ++n) {
            const int col = 16 * n + (int)lrow;
            if (col < 36) {
                #pragma unroll
                for (int i = 0; i < 4; ++i)
                    *(short*)&sOUT[(Rb + 4 * lkg + i) * 88 + col * 2] =
                        f2bf(acc2[n][i]);
            }
        }
    }

    // ---- part losses, minimal live set: on-demand loads (no cg[]/o[] arrays) ----
    // own out-row values: 2 bf16 per dword at col*2 (col even); c: float2 at cp+even
    const float* cp = cin + (size_t)(blockIdx.x * NT + t) * 36;
    float sp[5], np[5];
    {   // head (0,14,15); gt mixes x[:,15,0] and c[:,15,1] (faithful)
        unsigned w0  = *(const unsigned*)&sOUT[t * 88 + 0];
        unsigned w28 = *(const unsigned*)&sOUT[t * 88 + 56];
        unsigned w30 = *(const unsigned*)&sOUT[t * 88 + 60];
        float o0x = __uint_as_float(w0 << 16),  o0y = __uint_as_float(w0 & 0xFFFF0000u);
        float o28 = __uint_as_float(w28 << 16), o29 = __uint_as_float(w28 & 0xFFFF0000u);
        float o30 = __uint_as_float(w30 << 16), o31 = __uint_as_float(w30 & 0xFFFF0000u);
        float2 c0  = *(const float2*)(cp + 0);
        float2 c28 = *(const float2*)(cp + 28);
        float2 c30 = *(const float2*)(cp + 30);
        float dxa = o0x - o28, dya = o0y - o29;
        float dxb = o0x - o30, dyb = o0y - o31;
        float pred = 0.5f * (sqrtf(dxa*dxa + dya*dya) + sqrtf(dxb*dxb + dyb*dyb));
        float cxa = c0.x - c28.x, cya = c0.y - c28.y;
        float gxa = c0.x - o30,   gya = c0.y - c30.y;
        float gt = 0.5f * (sqrtf(cxa*cxa + cya*cya) + sqrtf(gxa*gxa + gya*gya));
        float vf = (c0.x != -1.f && c28.x != -1.f && c30.x != -1.f) ? 1.f : 0.f;
        float e = pred - gt;
        sp[0] = e * e * vf; np[0] = vf;
    }
    #pragma unroll
    for (int p = 0; p < 4; ++p) {
        const int a = 2 + 3 * p;   // b=a+1, cc=a+2; c/o indices 2a..2a+5
        unsigned wA = *(const unsigned*)&sOUT[t * 88 + 4 * a + 0];
        unsigned wB = *(const unsigned*)&sOUT[t * 88 + 4 * a + 4];
        unsigned wC = *(const unsigned*)&sOUT[t * 88 + 4 * a + 8];
        float oax = __uint_as_float(wA << 16), oay = __uint_as_float(wA & 0xFFFF0000u);
        float obx = __uint_as_float(wB << 16), oby = __uint_as_float(wB & 0xFFFF0000u);
        float ocx = __uint_as_float(wC << 16), ocy = __uint_as_float(wC & 0xFFFF0000u);
        float2 ca = *(const float2*)(cp + 2 * a);
        float2 cb = *(const float2*)(cp + 2 * a + 2);
        float2 cc2 = *(const float2*)(cp + 2 * a + 4);
        float dxa = oax - obx, dya = oay - oby;
        float dxb = obx - ocx, dyb = oby - ocy;
        float pred = 0.5f * (sqrtf(dxa*dxa + dya*dya) + sqrtf(dxb*dxb + dyb*dyb));
        float cxa = ca.x - cb.x, cya = ca.y - cb.y;
        float gxa = cb.x - ocx,  gya = cb.y - cc2.y;
        float gt = 0.5f * (sqrtf(cxa*cxa + cya*cya) + sqrtf(gxa*gxa + gya*gya));
        float vf = (ca.x != -1.f && cb.x != -1.f && cc2.x != -1.f) ? 1.f : 0.f;
        float e = pred - gt;
        sp[p + 1] = e * e * vf; np[p + 1] = vf;
    }

    __syncthreads();   // all waves' out-rows complete

    // ---- coalesced x store + miss store + elementwise kp-loss ----
    const size_t blkBase = (size_t)blockIdx.x * (NT * 36);
    const float4* cin4 = (const float4*)(cin + blkBase);
    const int4*   tm4  = (const int4*)(tmask + blkBase);
    float4*       x4   = (float4*)(xout + blkBase);
    float*        mo   = missout + blkBase;

    float s1 = 0.f, s2 = 0.f;
    #pragma unroll
    for (int i = 0; i < 9; ++i) {
        int g4 = i * NT + t;
        unsigned g = 4u * (unsigned)g4;
        unsigned row = g / 36u;
        unsigned col = g - row * 36u;          // col % 4 == 0 -> 8B aligned
        uint2 w = *(const uint2*)&sOUT[row * 88u + col * 2u];
        float4 xv;
        xv.x = __uint_as_float(w.x << 16);
        xv.y = __uint_as_float(w.x & 0xFFFF0000u);
        xv.z = __uint_as_float(w.y << 16);
        xv.w = __uint_as_float(w.y & 0xFFFF0000u);
        float4 cv = cin4[g4];
        int4   mv = tm4[g4];
        x4[g4] = xv;
        mo[g + 0] = (cv.x != -1.f) ? 1.f : 0.f;
        mo[g + 1] = (cv.y != -1.f) ? 1.f : 0.f;
        mo[g + 2] = (cv.z != -1.f) ? 1.f : 0.f;
        mo[g + 3] = (cv.w != -1.f) ? 1.f : 0.f;
        float m0 = (float)mv.x, m1_ = (float)mv.y, m2_ = (float)mv.z, m3_ = (float)mv.w;
        float d0 = xv.x - cv.x, d1 = xv.y - cv.y, d2 = xv.z - cv.z, d3 = xv.w - cv.w;
        s1 += d0*d0*m0 + d1*d1*m1_ + d2*d2*m2_ + d3*d3*m3_;
        s2 += m0 + m1_ + m2_ + m3_;
    }

    // ---- block reduction of 12 scalars (scratch = dead sT1 region) ----
    float rv[12] = { s1, s2, sp[0], np[0], sp[1], np[1],
                     sp[2], np[2], sp[3], np[3], sp[4], np[4] };
    #pragma unroll
    for (int v = 0; v < 12; ++v) {
        #pragma unroll
        for (int off = 32; off > 0; off >>= 1)
            rv[v] += __shfl_down(rv[v], off, 64);
    }
    if (lane == 0) {
        float* sw = (float*)(sT1 + wave * (16 * 144));
        #pragma unroll
        for (int v = 0; v < 12; ++v) sw[v] = rv[v];
    }
    __syncthreads();
    if (t < 12) {
        float s = 0.f;
        #pragma unroll
        for (int w = 0; w < 4; ++w) s += ((const float*)(sT1 + w * (16 * 144)))[t];
        partials[blockIdx.x * 12 + t] = s;
    }
}

__global__ __launch_bounds__(256) void kp_fin(const float* __restrict__ partials,
                                              float* __restrict__ total_out)
{
    __shared__ float sred[4][12];
    const int t = threadIdx.x;
    float rv[12];
    #pragma unroll
    for (int v = 0; v < 12; ++v) rv[v] = 0.f;
    for (int b = t; b < NB; b += 256) {
        #pragma unroll
        for (int v = 0; v < 12; ++v) rv[v] += partials[b * 12 + v];
    }
    #pragma unroll
    for (int v = 0; v < 12; ++v) {
        #pragma unroll
        for (int off = 32; off > 0; off >>= 1)
            rv[v] += __shfl_down(rv[v], off, 64);
    }
    const int wave = t >> 6, lane = t & 63;
    if (lane == 0) {
        #pragma unroll
        for (int v = 0; v < 12; ++v) sred[wave][v] = rv[v];
    }
    __syncthreads();
    if (t == 0) {
        float acc[12];
        #pragma unroll
        for (int v = 0; v < 12; ++v)
            acc[v] = sred[0][v] + sred[1][v] + sred[2][v] + sred[3][v];
        float total = acc[0] / acc[1];
        #pragma unroll
        for (int p = 0; p < 5; ++p) {
            float s = acc[2 + 2 * p], n = acc[3 + 2 * p];
            total += (n > 0.f) ? (s / fmaxf(n, 1.f)) : 0.f;
        }
        total_out[0] = total;
    }
}

extern "C" void kernel_launch(void* const* d_in, const int* in_sizes, int n_in,
                              void* d_out, int out_size, void* d_ws, size_t ws_size,
                              hipStream_t stream)
{
    const float* cin   = (const float*)d_in[0];
    const int*   tmask = (const int*)  d_in[1];
    const float* w1  = (const float*)d_in[2];
    const float* b1  = (const float*)d_in[3];
    const float* g1  = (const float*)d_in[4];
    const float* bt1 = (const float*)d_in[5];
    const float* m1  = (const float*)d_in[6];
    const float* v1  = (const float*)d_in[7];
    const float* w2  = (const float*)d_in[8];
    const float* b2  = (const float*)d_in[9];
    const float* g2  = (const float*)d_in[10];
    const float* bt2 = (const float*)d_in[11];
    const float* m2  = (const float*)d_in[12];
    const float* v2  = (const float*)d_in[13];
    const float* w3  = (const float*)d_in[14];
    const float* b3  = (const float*)d_in[15];
    const float* g3  = (const float*)d_in[16];
    const float* bt3 = (const float*)d_in[17];
    const float* m3  = (const float*)d_in[18];
    const float* v3  = (const float*)d_in[19];
    const float* fw1 = (const float*)d_in[20];
    const float* fb1 = (const float*)d_in[21];
    const float* fw2 = (const float*)d_in[22];
    const float* fb2 = (const float*)d_in[23];

    float* xout     = (float*)d_out;                       // [B,36]
    float* total    = (float*)d_out + (size_t)BTOT * 36;   // scalar
    float* missout  = total + 1;                           // [B,36] as f32 0/1

    float* wsB      = (float*)d_ws;
    short* frags    = (short*)((char*)d_ws + FRAGS_BYTE);
    float* partials = (float*)((char*)d_ws + PART_BYTE);   // [NB,12]

    kp_setup<<<8, 256, 0, stream>>>(
        w1, b1, g1, bt1, m1, v1,
        w2, b2, g2, bt2, m2, v2,
        w3, b3, g3, bt3, m3, v3,
        fw1, fb1, fw2, fb2, wsB, frags);

    kp_main<<<NB, NT, 0, stream>>>(cin, tmask, wsB, frags,
        xout, missout, partials);

    kp_fin<<<1, 256, 0, stream>>>(partials, total);
}

// Round 13
// 58.667 us; speedup vs baseline: 1.3441x; 1.3399x over previous
//
#include <hip/hip_runtime.h>

#define NB   1024
#define NT   256
#define BTOT 262144   // NB*NT == B

typedef __attribute__((ext_vector_type(8))) short short8;
typedef __attribute__((ext_vector_type(4))) float f32x4;

__device__ __forceinline__ float relu_(float x) { return fmaxf(x, 0.0f); }

__device__ __forceinline__ short f2bf(float x) {   // RNE f32->bf16
    unsigned u = __float_as_uint(x);
    return (short)((u + 0x7FFFu + ((u >> 16) & 1u)) >> 16);
}
__device__ __forceinline__ unsigned pk2bf(float a, float b) {
    return ((unsigned)(unsigned short)f2bf(a)) |
           (((unsigned)(unsigned short)f2bf(b)) << 16);
}
__device__ __forceinline__ short8 pack8(float a0,float a1,float a2,float a3,
                                        float a4,float a5,float a6,float a7) {
    short8 r;
    r[0]=f2bf(a0); r[1]=f2bf(a1); r[2]=f2bf(a2); r[3]=f2bf(a3);
    r[4]=f2bf(a4); r[5]=f2bf(a5); r[6]=f2bf(a6); r[7]=f2bf(a7);
    return r;
}

// d_ws byte map:
//  0    : (reserved)            | A0 packed bf16 pairs at dword 160
//  768  : 46 B-fragments x 512 shorts (bf16), biases folded as extra K-rows
//  47872: partials [NB*12] f32
#define A0_DW    160
#define FRAGS_BYTE 768
#define PART_BYTE 47872
#define NFRAG 46

__global__ __launch_bounds__(256) void kp_setup(
    const float* __restrict__ w1, const float* __restrict__ b1,
    const float* __restrict__ g1, const float* __restrict__ bt1,
    const float* __restrict__ m1, const float* __restrict__ v1,
    const float* __restrict__ w2, const float* __restrict__ b2,
    const float* __restrict__ g2, const float* __restrict__ bt2,
    const float* __restrict__ m2, const float* __restrict__ v2,
    const float* __restrict__ w3, const float* __restrict__ b3,
    const float* __restrict__ g3, const float* __restrict__ bt3,
    const float* __restrict__ m3, const float* __restrict__ v3,
    const float* __restrict__ fw1, const float* __restrict__ fb1,
    const float* __restrict__ fw2, const float* __restrict__ fb2,
    float* __restrict__ wsB, short* __restrict__ frags)
{
    __shared__ float w1f[180], b1f[10], a0f[10];
    __shared__ float w2f[400], b2f[20];
    __shared__ float w3f[1200], b3f[30];
    const int t = threadIdx.x;

    if (t < 10) {
        float s = g1[t] * rsqrtf(v1[t] + 1e-5f);
        float bb = (b1[t] - m1[t]) * s + bt1[t];
        b1f[t] = bb; a0f[t] = relu_(bb);
        for (int i = 0; i < 18; ++i) w1f[t * 18 + i] = w1[t * 18 + i] * s;
    } else if (t >= 64 && t < 84) {
        int o = t - 64;
        float s = g2[o] * rsqrtf(v2[o] + 1e-5f);
        b2f[o] = (b2[o] - m2[o]) * s + bt2[o];
        for (int i = 0; i < 20; ++i) w2f[o * 20 + i] = w2[o * 20 + i] * s;
    } else if (t >= 128 && t < 158) {
        int o = t - 128;
        float s = g3[o] * rsqrtf(v3[o] + 1e-5f);
        b3f[o] = (b3[o] - m3[o]) * s + bt3[o];
        for (int i = 0; i < 40; ++i) w3f[o * 40 + i] = w3[o * 40 + i] * s;
    }
    __syncthreads();

    if (blockIdx.x == 0 && t < 5)
        ((unsigned*)wsB)[A0_DW + t] = pk2bf(a0f[2 * t], a0f[2 * t + 1]);

    for (int e = blockIdx.x * 256 + t; e < NFRAG * 512; e += gridDim.x * 256) {
        int frag = e >> 9, l = (e >> 3) & 63, j = e & 7;
        float val = 0.f;
        if (frag < 4) {                       // conv1: K=36 + bias@36, N=20
            int p = frag, nt = p >> 1, kt = p & 1;
            int k = kt * 32 + (l >> 4) * 8 + j, n = nt * 16 + (l & 15);
            if (n < 20) {
                int o = n % 10, pp = n / 10;
                if (k < 36) { int i = k >> 1, s = k & 1; if (s == pp) val = w1f[o * 18 + i]; }
                else if (k == 36) val = b1f[o];
            }
        } else if (frag < 12) {               // conv2: K=40 + bias@40, N=60
            int p = frag - 4, nt = p >> 1, kt = p & 1;
            int k = kt * 32 + (l >> 4) * 8 + j, n = nt * 16 + (l & 15);
            if (n < 60) {
                int q = n / 20, o = n % 20;
                if (k < 40) { int pp = k / 10, i = k % 10, d = pp - q;
                              if (d == 0 || d == 1) val = w2f[o * 20 + i * 2 + d]; }
                else if (k == 40) val = b2f[o];
            }
        } else if (frag < 20) {               // conv3: K=60 + bias@60, N=60
            int p = frag - 12, nt = p >> 1, kt = p & 1;
            int k = kt * 32 + (l >> 4) * 8 + j, n = nt * 16 + (l & 15);
            if (n < 60) {
                int q = n / 30, o = n % 30;
                if (k < 60) { int pp = k / 20, i = k % 20, d = pp - q;
                              if (d == 0 || d == 1) val = w3f[o * 40 + i * 2 + d]; }
                else if (k == 60) val = b3f[o];
            }
        } else if (frag < 34) {               // fc1: K=60 + bias@60, N=100
            int p = frag - 20, n7 = p >> 1, kt = p & 1;
            int k = kt * 32 + (l >> 4) * 8 + j, col = n7 * 16 + (l & 15);
            if (col < 100) {
                if (k < 60) val = fw1[col * 60 + k];
                else if (k == 60) val = fb1[col];
            }
        } else {                              // fc2: K=100 + bias@100, N=36
            int p = frag - 34, n3 = p >> 2, kt = p & 3;
            int k = kt * 32 + (l >> 4) * 8 + j, col = n3 * 16 + (l & 15);
            if (col < 36) {
                if (k < 100) val = fw2[col * 100 + k];
                else if (k == 100) val = fb2[col];
            }
        }
        frags[e] = f2bf(val);
    }
}

__global__ __launch_bounds__(NT) void kp_main(
    const float* __restrict__ cin, const int* __restrict__ tmask,
    const float* __restrict__ wsB, const short* __restrict__ frags,
    float* __restrict__ xout, float* __restrict__ missout,
    float* __restrict__ partials)
{
    // 40960 B total = exactly 4 blocks/CU (LDS-wise)
    __shared__ __align__(16) unsigned char sOUT[NT * 88];       // out rows, bf16
    __shared__ __align__(16) unsigned char sT1[4 * 16 * 144];   // a1 tiles (per-wave)
    __shared__ __align__(16) unsigned char sT2[4 * 16 * 144];   // a2/f/z tiles

    const int t = threadIdx.x;
    const int lane = t & 63, wave = t >> 6;
    const unsigned lrow = (unsigned)(lane & 15);
    const unsigned lkg  = (unsigned)(lane >> 4);
    const unsigned wbase = (unsigned)(t & ~63);
    const short8* frg = (const short8*)frags;

    unsigned char* T1 = sT1 + wave * (16 * 144);
    unsigned char* T2 = sT2 + wave * (16 * 144);

    // ---- one-time wave-private tile init (A0 regs die after this block) ----
    // T1: zero cols 40..71, col40=1.0, A0 constants cols 0..9 & 30..39.
    // T2: zero cols 60..71 (col60 re-set per tile; 61..63 rewritten by z).
    {
        const unsigned* a0p = (const unsigned*)wsB + A0_DW;
        uint4 A0q = *(const uint4*)a0p;
        unsigned A0e = a0p[4];
        if (lane < 16) {
            unsigned char* b = &T1[(unsigned)lane * 144];
            uint4 z4 = make_uint4(0u, 0u, 0u, 0u);
            *(uint4*)(b + 80)  = z4;
            *(uint4*)(b + 96)  = z4;
            *(uint4*)(b + 112) = z4;
            *(uint4*)(b + 128) = z4;
            *(unsigned*)(b + 80) = 0x00003F80u;                       // col 40 = 1.0
            *(uint4*)(b + 0)  = A0q;                                  // cols 0..7
            *(unsigned*)(b + 16) = A0e;                               // cols 8..9
            *(unsigned*)(b + 60) = A0q.x;                             // cols 30..31
            *(uint4*)(b + 64) = make_uint4(A0q.y, A0q.z, A0q.w, A0e); // cols 32..39
            unsigned char* b2 = &T2[(unsigned)lane * 144];
            *(uint2*)(b2 + 120) = make_uint2(0u, 0u);
            *(uint4*)(b2 + 128) = z4;
        }
    }

    #pragma unroll 1
    for (int m = 0; m < 4; ++m) {
        const unsigned Rb = wbase + 16u * (unsigned)m;

        // ---- conv1 A-frags straight from global ----
        const float* crow = cin + (size_t)(blockIdx.x * NT + Rb + lrow) * 36;
        float4 qa = *(const float4*)(crow + 8 * lkg);
        float4 qb = *(const float4*)(crow + 8 * lkg + 4);
        float4 qc = *(const float4*)(crow + 32);
        short8 Aa = pack8(qa.x, qa.y, qa.z, qa.w, qb.x, qb.y, qb.z, qb.w);
        float sf = (lkg == 0u) ? 1.f : 0.f;
        short8 Ab = pack8(qc.x * sf, qc.y * sf, qc.z * sf, qc.w * sf, sf, 0.f, 0.f, 0.f);

        // T2 col 60 = 1.0 (bias-one for conv3/fc1), re-set each tile (z destroys it)
        if (lane < 16)
            *(unsigned*)&T2[lane * 144 + 120] = 0x00003F80u;

        // ---- conv1 -> a1 (T1 cols 10..29) ----
        {
            f32x4 D1[2];
            #pragma unroll
            for (int nt = 0; nt < 2; ++nt) {
                D1[nt] = (f32x4){0.f, 0.f, 0.f, 0.f};
                D1[nt] = __builtin_amdgcn_mfma_f32_16x16x32_bf16(Aa, frg[(nt * 2 + 0) * 64 + lane], D1[nt], 0, 0, 0);
                D1[nt] = __builtin_amdgcn_mfma_f32_16x16x32_bf16(Ab, frg[(nt * 2 + 1) * 64 + lane], D1[nt], 0, 0, 0);
            }
            #pragma unroll
            for (int nt = 0; nt < 2; ++nt) {
                int n1 = nt * 16 + (int)lrow;
                if (n1 < 20) {
                    #pragma unroll
                    for (int i = 0; i < 4; ++i)
                        *(short*)&T1[(4 * lkg + i) * 144 + (n1 + 10) * 2] =
                            f2bf(relu_(D1[nt][i]));
                }
            }
        }

        // ---- conv2: A = a1 (K=41) -> a2 (T2 cols 0..59) ----
        Aa = *(const short8*)&T1[lrow * 144 + lkg * 16u];
        Ab = *(const short8*)&T1[lrow * 144 + 64u + lkg * 16u];
        {
            f32x4 D2[4];
            #pragma unroll
            for (int nt = 0; nt < 4; ++nt) {
                D2[nt] = (f32x4){0.f, 0.f, 0.f, 0.f};
                D2[nt] = __builtin_amdgcn_mfma_f32_16x16x32_bf16(Aa, frg[(4 + nt * 2 + 0) * 64 + lane], D2[nt], 0, 0, 0);
                D2[nt] = __builtin_amdgcn_mfma_f32_16x16x32_bf16(Ab, frg[(4 + nt * 2 + 1) * 64 + lane], D2[nt], 0, 0, 0);
            }
            #pragma unroll
            for (int nt = 0; nt < 4; ++nt) {
                int n2 = nt * 16 + (int)lrow;
                if (n2 < 60) {
                    #pragma unroll
                    for (int i = 0; i < 4; ++i)
                        *(short*)&T2[(4 * lkg + i) * 144 + n2 * 2] =
                            f2bf(relu_(D2[nt][i]));
                }
            }
        }

        // ---- conv3: A = a2 (K=61) -> f (T2, kf = 2*(n%30)+n/30) ----
        Aa = *(const short8*)&T2[lrow * 144 + lkg * 16u];
        Ab = *(const short8*)&T2[lrow * 144 + 64u + lkg * 16u];
        {
            f32x4 D3[4];
            #pragma unroll
            for (int nt = 0; nt < 4; ++nt) {
                D3[nt] = (f32x4){0.f, 0.f, 0.f, 0.f};
                D3[nt] = __builtin_amdgcn_mfma_f32_16x16x32_bf16(Aa, frg[(12 + nt * 2 + 0) * 64 + lane], D3[nt], 0, 0, 0);
                D3[nt] = __builtin_amdgcn_mfma_f32_16x16x32_bf16(Ab, frg[(12 + nt * 2 + 1) * 64 + lane], D3[nt], 0, 0, 0);
            }
            #pragma unroll
            for (int nt = 0; nt < 4; ++nt) {
                int n3 = nt * 16 + (int)lrow;
                if (n3 < 60) {
                    int o = (n3 >= 30) ? n3 - 30 : n3;
                    int kf = 2 * o + (n3 >= 30 ? 1 : 0);
                    #pragma unroll
                    for (int i = 0; i < 4; ++i)
                        *(short*)&T2[(4 * lkg + i) * 144 + kf * 2] =
                            f2bf(relu_(D3[nt][i]));
                }
            }
        }

        // ---- fc1 + fc2 (A = f, K=61; z K=101 with z[100]=1) ----
        // fc1 is computed PER-nn (acc1 never materialized as [4]): -12 VGPR peak
        short8 Fa = *(const short8*)&T2[lrow * 144 + lkg * 16u];
        short8 Fb = *(const short8*)&T2[lrow * 144 + 64u + lkg * 16u];
        f32x4 acc2[3];
        #pragma unroll
        for (int n = 0; n < 3; ++n) acc2[n] = (f32x4){0.f, 0.f, 0.f, 0.f};

        #pragma unroll
        for (int h = 0; h < 2; ++h) {
            #pragma unroll
            for (int nn = 0; nn < 4; ++nn) {
                const int n = 4 * h + nn;
                f32x4 a1v = (f32x4){0.f, 0.f, 0.f, 0.f};
                if (n < 7) {
                    a1v = __builtin_amdgcn_mfma_f32_16x16x32_bf16(Fa, frg[(20 + n * 2 + 0) * 64 + lane], a1v, 0, 0, 0);
                    a1v = __builtin_amdgcn_mfma_f32_16x16x32_bf16(Fb, frg[(20 + n * 2 + 1) * 64 + lane], a1v, 0, 0, 0);
                }
                #pragma unroll
                for (int i = 0; i < 4; ++i) {
                    float zv = (n < 7) ? relu_(a1v[i]) : 0.f;
                    if (n == 6 && (int)lrow == 4) zv = 1.f;   // z[100] = bias-one
                    *(short*)&T2[(4 * lkg + i) * 144 + (16 * nn + (int)lrow) * 2] = f2bf(zv);
                }
            }
            #pragma unroll
            for (int q = 0; q < 2; ++q) {
                const int kt = 2 * h + q;
                short8 Az = *(const short8*)&T2[lrow * 144 + (unsigned)(q * 64) + lkg * 16u];
                #pragma unroll
                for (int n = 0; n < 3; ++n)
                    acc2[n] = __builtin_amdgcn_mfma_f32_16x16x32_bf16(Az, frg[(34 + n * 4 + kt) * 64 + lane], acc2[n], 0, 0, 0);
            }
        }

        // out (bf16) -> sOUT rows of this tile
        #pragma unroll
        for (int n = 0; n < 3; ++n) {
            const int col = 16 * n + (int)lrow;
            if (col < 36) {
                #pragma unroll
                for (int i = 0; i < 4; ++i)
                    *(short*)&sOUT[(Rb + 4 * lkg + i) * 88 + col * 2] =
                        f2bf(acc2[n][i]);
            }
        }
    }

    // ---- part losses, minimal live set: on-demand loads ----
    const float* cp = cin + (size_t)(blockIdx.x * NT + t) * 36;
    float sp[5], np[5];
    {   // head (0,14,15); gt mixes x[:,15,0] and c[:,15,1] (faithful)
        unsigned w0  = *(const unsigned*)&sOUT[t * 88 + 0];
        unsigned w28 = *(const unsigned*)&sOUT[t * 88 + 56];
        unsigned w30 = *(const unsigned*)&sOUT[t * 88 + 60];
        float o0x = __uint_as_float(w0 << 16),  o0y = __uint_as_float(w0 & 0xFFFF0000u);
        float o28 = __uint_as_float(w28 << 16), o29 = __uint_as_float(w28 & 0xFFFF0000u);
        float o30 = __uint_as_float(w30 << 16), o31 = __uint_as_float(w30 & 0xFFFF0000u);
        float2 c0  = *(const float2*)(cp + 0);
        float2 c28 = *(const float2*)(cp + 28);
        float2 c30 = *(const float2*)(cp + 30);
        float dxa = o0x - o28, dya = o0y - o29;
        float dxb = o0x - o30, dyb = o0y - o31;
        float pred = 0.5f * (sqrtf(dxa*dxa + dya*dya) + sqrtf(dxb*dxb + dyb*dyb));
        float cxa = c0.x - c28.x, cya = c0.y - c28.y;
        float gxa = c0.x - o30,   gya = c0.y - c30.y;
        float gt = 0.5f * (sqrtf(cxa*cxa + cya*cya) + sqrtf(gxa*gxa + gya*gya));
        float vf = (c0.x != -1.f && c28.x != -1.f && c30.x != -1.f) ? 1.f : 0.f;
        float e = pred - gt;
        sp[0] = e * e * vf; np[0] = vf;
    }
    #pragma unroll
    for (int p = 0; p < 4; ++p) {
        const int a = 2 + 3 * p;   // b=a+1, cc=a+2
        unsigned wA = *(const unsigned*)&sOUT[t * 88 + 4 * a + 0];
        unsigned wB = *(const unsigned*)&sOUT[t * 88 + 4 * a + 4];
        unsigned wC = *(const unsigned*)&sOUT[t * 88 + 4 * a + 8];
        float oax = __uint_as_float(wA << 16), oay = __uint_as_float(wA & 0xFFFF0000u);
        float obx = __uint_as_float(wB << 16), oby = __uint_as_float(wB & 0xFFFF0000u);
        float ocx = __uint_as_float(wC << 16), ocy = __uint_as_float(wC & 0xFFFF0000u);
        float2 ca = *(const float2*)(cp + 2 * a);
        float2 cb = *(const float2*)(cp + 2 * a + 2);
        float2 cc2 = *(const float2*)(cp + 2 * a + 4);
        float dxa = oax - obx, dya = oay - oby;
        float dxb = obx - ocx, dyb = oby - ocy;
        float pred = 0.5f * (sqrtf(dxa*dxa + dya*dya) + sqrtf(dxb*dxb + dyb*dyb));
        float cxa = ca.x - cb.x, cya = ca.y - cb.y;
        float gxa = cb.x - ocx,  gya = cb.y - cc2.y;
        float gt = 0.5f * (sqrtf(cxa*cxa + cya*cya) + sqrtf(gxa*gxa + gya*gya));
        float vf = (ca.x != -1.f && cb.x != -1.f && cc2.x != -1.f) ? 1.f : 0.f;
        float e = pred - gt;
        sp[p + 1] = e * e * vf; np[p + 1] = vf;
    }

    __syncthreads();   // all waves' out-rows complete

    // ---- coalesced x store + miss store + elementwise kp-loss ----
    const size_t blkBase = (size_t)blockIdx.x * (NT * 36);
    const float4* cin4 = (const float4*)(cin + blkBase);
    const int4*   tm4  = (const int4*)(tmask + blkBase);
    float4*       x4   = (float4*)(xout + blkBase);
    float*        mo   = missout + blkBase;

    float s1 = 0.f, s2 = 0.f;
    #pragma unroll
    for (int i = 0; i < 9; ++i) {
        int g4 = i * NT + t;
        unsigned g = 4u * (unsigned)g4;
        unsigned row = g / 36u;
        unsigned col = g - row * 36u;          // col % 4 == 0 -> 8B aligned
        uint2 w = *(const uint2*)&sOUT[row * 88u + col * 2u];
        float4 xv;
        xv.x = __uint_as_float(w.x << 16);
        xv.y = __uint_as_float(w.x & 0xFFFF0000u);
        xv.z = __uint_as_float(w.y << 16);
        xv.w = __uint_as_float(w.y & 0xFFFF0000u);
        float4 cv = cin4[g4];
        int4   mv = tm4[g4];
        x4[g4] = xv;
        mo[g + 0] = (cv.x != -1.f) ? 1.f : 0.f;
        mo[g + 1] = (cv.y != -1.f) ? 1.f : 0.f;
        mo[g + 2] = (cv.z != -1.f) ? 1.f : 0.f;
        mo[g + 3] = (cv.w != -1.f) ? 1.f : 0.f;
        float m0 = (float)mv.x, m1_ = (float)mv.y, m2_ = (float)mv.z, m3_ = (float)mv.w;
        float d0 = xv.x - cv.x, d1 = xv.y - cv.y, d2 = xv.z - cv.z, d3 = xv.w - cv.w;
        s1 += d0*d0*m0 + d1*d1*m1_ + d2*d2*m2_ + d3*d3*m3_;
        s2 += m0 + m1_ + m2_ + m3_;
    }

    // ---- block reduction of 12 scalars (scratch = dead sT1 region) ----
    float rv[12] = { s1, s2, sp[0], np[0], sp[1], np[1],
                     sp[2], np[2], sp[3], np[3], sp[4], np[4] };
    #pragma unroll
    for (int v = 0; v < 12; ++v) {
        #pragma unroll
        for (int off = 32; off > 0; off >>= 1)
            rv[v] += __shfl_down(rv[v], off, 64);
    }
    if (lane == 0) {
        float* sw = (float*)(sT1 + wave * (16 * 144));
        #pragma unroll
        for (int v = 0; v < 12; ++v) sw[v] = rv[v];
    }
    __syncthreads();
    if (t < 12) {
        float s = 0.f;
        #pragma unroll
        for (int w = 0; w < 4; ++w) s += ((const float*)(sT1 + w * (16 * 144)))[t];
        partials[blockIdx.x * 12 + t] = s;
    }
}

__global__ __launch_bounds__(256) void kp_fin(const float* __restrict__ partials,
                                              float* __restrict__ total_out)
{
    __shared__ float sred[4][12];
    const int t = threadIdx.x;
    float rv[12];
    #pragma unroll
    for (int v = 0; v < 12; ++v) rv[v] = 0.f;
    for (int b = t; b < NB; b += 256) {
        #pragma unroll
        for (int v = 0; v < 12; ++v) rv[v] += partials[b * 12 + v];
    }
    #pragma unroll
    for (int v = 0; v < 12; ++v) {
        #pragma unroll
        for (int off = 32; off > 0; off >>= 1)
            rv[v] += __shfl_down(rv[v], off, 64);
    }
    const int wave = t >> 6, lane = t & 63;
    if (lane == 0) {
        #pragma unroll
        for (int v = 0; v < 12; ++v) sred[wave][v] = rv[v];
    }
    __syncthreads();
    if (t == 0) {
        float acc[12];
        #pragma unroll
        for (int v = 0; v < 12; ++v)
            acc[v] = sred[0][v] + sred[1][v] + sred[2][v] + sred[3][v];
        float total = acc[0] / acc[1];
        #pragma unroll
        for (int p = 0; p < 5; ++p) {
            float s = acc[2 + 2 * p], n = acc[3 + 2 * p];
            total += (n > 0.f) ? (s / fmaxf(n, 1.f)) : 0.f;
        }
        total_out[0] = total;
    }
}

extern "C" void kernel_launch(void* const* d_in, const int* in_sizes, int n_in,
                              void* d_out, int out_size, void* d_ws, size_t ws_size,
                              hipStream_t stream)
{
    const float* cin   = (const float*)d_in[0];
    const int*   tmask = (const int*)  d_in[1];
    const float* w1  = (const float*)d_in[2];
    const float* b1  = (const float*)d_in[3];
    const float* g1  = (const float*)d_in[4];
    const float* bt1 = (const float*)d_in[5];
    const float* m1  = (const float*)d_in[6];
    const float* v1  = (const float*)d_in[7];
    const float* w2  = (const float*)d_in[8];
    const float* b2  = (const float*)d_in[9];
    const float* g2  = (const float*)d_in[10];
    const float* bt2 = (const float*)d_in[11];
    const float* m2  = (const float*)d_in[12];
    const float* v2  = (const float*)d_in[13];
    const float* w3  = (const float*)d_in[14];
    const float* b3  = (const float*)d_in[15];
    const float* g3  = (const float*)d_in[16];
    const float* bt3 = (const float*)d_in[17];
    const float* m3  = (const float*)d_in[18];
    const float* v3  = (const float*)d_in[19];
    const float* fw1 = (const float*)d_in[20];
    const float* fb1 = (const float*)d_in[21];
    const float* fw2 = (const float*)d_in[22];
    const float* fb2 = (const float*)d_in[23];

    float* xout     = (float*)d_out;                       // [B,36]
    float* total    = (float*)d_out + (size_t)BTOT * 36;   // scalar
    float* missout  = total + 1;                           // [B,36] as f32 0/1

    float* wsB      = (float*)d_ws;
    short* frags    = (short*)((char*)d_ws + FRAGS_BYTE);
    float* partials = (float*)((char*)d_ws + PART_BYTE);   // [NB,12]

    kp_setup<<<8, 256, 0, stream>>>(
        w1, b1, g1, bt1, m1, v1,
        w2, b2, g2, bt2, m2, v2,
        w3, b3, g3, bt3, m3, v3,
        fw1, fb1, fw2, fb2, wsB, frags);

    kp_main<<<NB, NT, 0, stream>>>(cin, tmask, wsB, frags,
        xout, missout, partials);

    kp_fin<<<1, 256, 0, stream>>>(partials, total);
}

// Round 14
// 56.968 us; speedup vs baseline: 1.3841x; 1.0298x over previous
//
#include <hip/hip_runtime.h>
#include <hip/hip_bf16.h>

#define NB   1024
#define NT   256
#define BTOT 262144   // NB*NT == B

typedef __attribute__((ext_vector_type(8))) short short8;
typedef __attribute__((ext_vector_type(4))) float f32x4;

__device__ __forceinline__ float relu_(float x) { return fmaxf(x, 0.0f); }

// setup-kernel-only (portable RNE); hot path uses native casts below
__device__ __forceinline__ short f2bf(float x) {
    unsigned u = __float_as_uint(x);
    return (short)((u + 0x7FFFu + ((u >> 16) & 1u)) >> 16);
}
__device__ __forceinline__ unsigned pk2bf(float a, float b) {
    return ((unsigned)(unsigned short)f2bf(a)) |
           (((unsigned)(unsigned short)f2bf(b)) << 16);
}

// hot-path conversions: scalar casts -> compiler emits HW v_cvt_pk_bf16_f32
// (m240: cast form is FASTER than hand-written bit-manip or inline asm)
__device__ __forceinline__ void st_bf16(unsigned char* p, float x) {
    *(__hip_bfloat16*)p = __float2bfloat16(x);
}
__device__ __forceinline__ unsigned pkbf(float a, float b) {
    __hip_bfloat162 h = __float22bfloat162_rn(make_float2(a, b));
    return *(unsigned*)&h;
}
__device__ __forceinline__ short8 pack8(float a0,float a1,float a2,float a3,
                                        float a4,float a5,float a6,float a7) {
    uint4 v = make_uint4(pkbf(a0,a1), pkbf(a2,a3), pkbf(a4,a5), pkbf(a6,a7));
    return *(short8*)&v;
}

// d_ws byte map:
//  0    : (reserved)            | A0 packed bf16 pairs at dword 160
//  768  : 46 B-fragments x 512 shorts (bf16), biases folded as extra K-rows
//  47872: partials [NB*12] f32
#define A0_DW    160
#define FRAGS_BYTE 768
#define PART_BYTE 47872
#define NFRAG 46

__global__ __launch_bounds__(256) void kp_setup(
    const float* __restrict__ w1, const float* __restrict__ b1,
    const float* __restrict__ g1, const float* __restrict__ bt1,
    const float* __restrict__ m1, const float* __restrict__ v1,
    const float* __restrict__ w2, const float* __restrict__ b2,
    const float* __restrict__ g2, const float* __restrict__ bt2,
    const float* __restrict__ m2, const float* __restrict__ v2,
    const float* __restrict__ w3, const float* __restrict__ b3,
    const float* __restrict__ g3, const float* __restrict__ bt3,
    const float* __restrict__ m3, const float* __restrict__ v3,
    const float* __restrict__ fw1, const float* __restrict__ fb1,
    const float* __restrict__ fw2, const float* __restrict__ fb2,
    float* __restrict__ wsB, short* __restrict__ frags)
{
    __shared__ float w1f[180], b1f[10], a0f[10];
    __shared__ float w2f[400], b2f[20];
    __shared__ float w3f[1200], b3f[30];
    const int t = threadIdx.x;

    if (t < 10) {
        float s = g1[t] * rsqrtf(v1[t] + 1e-5f);
        float bb = (b1[t] - m1[t]) * s + bt1[t];
        b1f[t] = bb; a0f[t] = relu_(bb);
        for (int i = 0; i < 18; ++i) w1f[t * 18 + i] = w1[t * 18 + i] * s;
    } else if (t >= 64 && t < 84) {
        int o = t - 64;
        float s = g2[o] * rsqrtf(v2[o] + 1e-5f);
        b2f[o] = (b2[o] - m2[o]) * s + bt2[o];
        for (int i = 0; i < 20; ++i) w2f[o * 20 + i] = w2[o * 20 + i] * s;
    } else if (t >= 128 && t < 158) {
        int o = t - 128;
        float s = g3[o] * rsqrtf(v3[o] + 1e-5f);
        b3f[o] = (b3[o] - m3[o]) * s + bt3[o];
        for (int i = 0; i < 40; ++i) w3f[o * 40 + i] = w3[o * 40 + i] * s;
    }
    __syncthreads();

    if (blockIdx.x == 0 && t < 5)
        ((unsigned*)wsB)[A0_DW + t] = pk2bf(a0f[2 * t], a0f[2 * t + 1]);

    for (int e = blockIdx.x * 256 + t; e < NFRAG * 512; e += gridDim.x * 256) {
        int frag = e >> 9, l = (e >> 3) & 63, j = e & 7;
        float val = 0.f;
        if (frag < 4) {                       // conv1: K=36 + bias@36, N=20
            int p = frag, nt = p >> 1, kt = p & 1;
            int k = kt * 32 + (l >> 4) * 8 + j, n = nt * 16 + (l & 15);
            if (n < 20) {
                int o = n % 10, pp = n / 10;
                if (k < 36) { int i = k >> 1, s = k & 1; if (s == pp) val = w1f[o * 18 + i]; }
                else if (k == 36) val = b1f[o];
            }
        } else if (frag < 12) {               // conv2: K=40 + bias@40, N=60
            int p = frag - 4, nt = p >> 1, kt = p & 1;
            int k = kt * 32 + (l >> 4) * 8 + j, n = nt * 16 + (l & 15);
            if (n < 60) {
                int q = n / 20, o = n % 20;
                if (k < 40) { int pp = k / 10, i = k % 10, d = pp - q;
                              if (d == 0 || d == 1) val = w2f[o * 20 + i * 2 + d]; }
                else if (k == 40) val = b2f[o];
            }
        } else if (frag < 20) {               // conv3: K=60 + bias@60, N=60
            int p = frag - 12, nt = p >> 1, kt = p & 1;
            int k = kt * 32 + (l >> 4) * 8 + j, n = nt * 16 + (l & 15);
            if (n < 60) {
                int q = n / 30, o = n % 30;
                if (k < 60) { int pp = k / 20, i = k % 20, d = pp - q;
                              if (d == 0 || d == 1) val = w3f[o * 40 + i * 2 + d]; }
                else if (k == 60) val = b3f[o];
            }
        } else if (frag < 34) {               // fc1: K=60 + bias@60, N=100
            int p = frag - 20, n7 = p >> 1, kt = p & 1;
            int k = kt * 32 + (l >> 4) * 8 + j, col = n7 * 16 + (l & 15);
            if (col < 100) {
                if (k < 60) val = fw1[col * 60 + k];
                else if (k == 60) val = fb1[col];
            }
        } else {                              // fc2: K=100 + bias@100, N=36
            int p = frag - 34, n3 = p >> 2, kt = p & 3;
            int k = kt * 32 + (l >> 4) * 8 + j, col = n3 * 16 + (l & 15);
            if (col < 36) {
                if (k < 100) val = fw2[col * 100 + k];
                else if (k == 100) val = fb2[col];
            }
        }
        frags[e] = f2bf(val);
    }
}

__global__ __launch_bounds__(NT) void kp_main(
    const float* __restrict__ cin, const int* __restrict__ tmask,
    const float* __restrict__ wsB, const short* __restrict__ frags,
    float* __restrict__ xout, float* __restrict__ missout,
    float* __restrict__ partials)
{
    // 40960 B total = exactly 4 blocks/CU (LDS-wise)
    __shared__ __align__(16) unsigned char sOUT[NT * 88];       // out rows, bf16
    __shared__ __align__(16) unsigned char sT1[4 * 16 * 144];   // a1 tiles (per-wave)
    __shared__ __align__(16) unsigned char sT2[4 * 16 * 144];   // a2/f/z tiles

    const int t = threadIdx.x;
    const int lane = t & 63, wave = t >> 6;
    const unsigned lrow = (unsigned)(lane & 15);
    const unsigned lkg  = (unsigned)(lane >> 4);
    const unsigned wbase = (unsigned)(t & ~63);
    const short8* frg = (const short8*)frags;

    unsigned char* T1 = sT1 + wave * (16 * 144);
    unsigned char* T2 = sT2 + wave * (16 * 144);

    // ---- one-time wave-private tile init (A0 regs die after this block) ----
    {
        const unsigned* a0p = (const unsigned*)wsB + A0_DW;
        uint4 A0q = *(const uint4*)a0p;
        unsigned A0e = a0p[4];
        if (lane < 16) {
            unsigned char* b = &T1[(unsigned)lane * 144];
            uint4 z4 = make_uint4(0u, 0u, 0u, 0u);
            *(uint4*)(b + 80)  = z4;
            *(uint4*)(b + 96)  = z4;
            *(uint4*)(b + 112) = z4;
            *(uint4*)(b + 128) = z4;
            *(unsigned*)(b + 80) = 0x00003F80u;                       // col 40 = 1.0
            *(uint4*)(b + 0)  = A0q;                                  // cols 0..7
            *(unsigned*)(b + 16) = A0e;                               // cols 8..9
            *(unsigned*)(b + 60) = A0q.x;                             // cols 30..31
            *(uint4*)(b + 64) = make_uint4(A0q.y, A0q.z, A0q.w, A0e); // cols 32..39
            unsigned char* b2 = &T2[(unsigned)lane * 144];
            *(uint2*)(b2 + 120) = make_uint2(0u, 0u);
            *(uint4*)(b2 + 128) = z4;
        }
    }

    #pragma unroll 1
    for (int m = 0; m < 4; ++m) {
        const unsigned Rb = wbase + 16u * (unsigned)m;

        // ---- conv1 A-frags straight from global ----
        const float* crow = cin + (size_t)(blockIdx.x * NT + Rb + lrow) * 36;
        float4 qa = *(const float4*)(crow + 8 * lkg);
        float4 qb = *(const float4*)(crow + 8 * lkg + 4);
        float4 qc = *(const float4*)(crow + 32);
        short8 Aa = pack8(qa.x, qa.y, qa.z, qa.w, qb.x, qb.y, qb.z, qb.w);
        float sf = (lkg == 0u) ? 1.f : 0.f;
        short8 Ab = pack8(qc.x * sf, qc.y * sf, qc.z * sf, qc.w * sf, sf, 0.f, 0.f, 0.f);

        // T2 col 60 = 1.0 (bias-one for conv3/fc1), re-set each tile (z destroys it)
        if (lane < 16)
            *(unsigned*)&T2[lane * 144 + 120] = 0x00003F80u;

        // ---- conv1 -> a1 (T1 cols 10..29) ----
        {
            f32x4 D1[2];
            #pragma unroll
            for (int nt = 0; nt < 2; ++nt) {
                D1[nt] = (f32x4){0.f, 0.f, 0.f, 0.f};
                D1[nt] = __builtin_amdgcn_mfma_f32_16x16x32_bf16(Aa, frg[(nt * 2 + 0) * 64 + lane], D1[nt], 0, 0, 0);
                D1[nt] = __builtin_amdgcn_mfma_f32_16x16x32_bf16(Ab, frg[(nt * 2 + 1) * 64 + lane], D1[nt], 0, 0, 0);
            }
            #pragma unroll
            for (int nt = 0; nt < 2; ++nt) {
                int n1 = nt * 16 + (int)lrow;
                if (n1 < 20) {
                    #pragma unroll
                    for (int i = 0; i < 4; ++i)
                        st_bf16(&T1[(4 * lkg + i) * 144 + (n1 + 10) * 2],
                                relu_(D1[nt][i]));
                }
            }
        }

        // ---- conv2: A = a1 (K=41) -> a2 (T2 cols 0..59) ----
        Aa = *(const short8*)&T1[lrow * 144 + lkg * 16u];
        Ab = *(const short8*)&T1[lrow * 144 + 64u + lkg * 16u];
        {
            f32x4 D2[4];
            #pragma unroll
            for (int nt = 0; nt < 4; ++nt) {
                D2[nt] = (f32x4){0.f, 0.f, 0.f, 0.f};
                D2[nt] = __builtin_amdgcn_mfma_f32_16x16x32_bf16(Aa, frg[(4 + nt * 2 + 0) * 64 + lane], D2[nt], 0, 0, 0);
                D2[nt] = __builtin_amdgcn_mfma_f32_16x16x32_bf16(Ab, frg[(4 + nt * 2 + 1) * 64 + lane], D2[nt], 0, 0, 0);
            }
            #pragma unroll
            for (int nt = 0; nt < 4; ++nt) {
                int n2 = nt * 16 + (int)lrow;
                if (n2 < 60) {
                    #pragma unroll
                    for (int i = 0; i < 4; ++i)
                        st_bf16(&T2[(4 * lkg + i) * 144 + n2 * 2],
                                relu_(D2[nt][i]));
                }
            }
        }

        // ---- conv3: A = a2 (K=61) -> f (T2, kf = 2*(n%30)+n/30) ----
        Aa = *(const short8*)&T2[lrow * 144 + lkg * 16u];
        Ab = *(const short8*)&T2[lrow * 144 + 64u + lkg * 16u];
        {
            f32x4 D3[4];
            #pragma unroll
            for (int nt = 0; nt < 4; ++nt) {
                D3[nt] = (f32x4){0.f, 0.f, 0.f, 0.f};
                D3[nt] = __builtin_amdgcn_mfma_f32_16x16x32_bf16(Aa, frg[(12 + nt * 2 + 0) * 64 + lane], D3[nt], 0, 0, 0);
                D3[nt] = __builtin_amdgcn_mfma_f32_16x16x32_bf16(Ab, frg[(12 + nt * 2 + 1) * 64 + lane], D3[nt], 0, 0, 0);
            }
            #pragma unroll
            for (int nt = 0; nt < 4; ++nt) {
                int n3 = nt * 16 + (int)lrow;
                if (n3 < 60) {
                    int o = (n3 >= 30) ? n3 - 30 : n3;
                    int kf = 2 * o + (n3 >= 30 ? 1 : 0);
                    #pragma unroll
                    for (int i = 0; i < 4; ++i)
                        st_bf16(&T2[(4 * lkg + i) * 144 + kf * 2],
                                relu_(D3[nt][i]));
                }
            }
        }

        // ---- fc1 + fc2 (A = f, K=61; z K=101 with z[100]=1) ----
        short8 Fa = *(const short8*)&T2[lrow * 144 + lkg * 16u];
        short8 Fb = *(const short8*)&T2[lrow * 144 + 64u + lkg * 16u];
        f32x4 acc2[3];
        #pragma unroll
        for (int n = 0; n < 3; ++n) acc2[n] = (f32x4){0.f, 0.f, 0.f, 0.f};

        #pragma unroll
        for (int h = 0; h < 2; ++h) {
            #pragma unroll
            for (int nn = 0; nn < 4; ++nn) {
                const int n = 4 * h + nn;
                f32x4 a1v = (f32x4){0.f, 0.f, 0.f, 0.f};
                if (n < 7) {
                    a1v = __builtin_amdgcn_mfma_f32_16x16x32_bf16(Fa, frg[(20 + n * 2 + 0) * 64 + lane], a1v, 0, 0, 0);
                    a1v = __builtin_amdgcn_mfma_f32_16x16x32_bf16(Fb, frg[(20 + n * 2 + 1) * 64 + lane], a1v, 0, 0, 0);
                }
                #pragma unroll
                for (int i = 0; i < 4; ++i) {
                    float zv = (n < 7) ? relu_(a1v[i]) : 0.f;
                    if (n == 6 && (int)lrow == 4) zv = 1.f;   // z[100] = bias-one
                    st_bf16(&T2[(4 * lkg + i) * 144 + (16 * nn + (int)lrow) * 2], zv);
                }
            }
            #pragma unroll
            for (int q = 0; q < 2; ++q) {
                const int kt = 2 * h + q;
                short8 Az = *(const short8*)&T2[lrow * 144 + (unsigned)(q * 64) + lkg * 16u];
                #pragma unroll
                for (int n = 0; n < 3; ++n)
                    acc2[n] = __builtin_amdgcn_mfma_f32_16x16x32_bf16(Az, frg[(34 + n * 4 + kt) * 64 + lane], acc2[n], 0, 0, 0);
            }
        }

        // out (bf16) -> sOUT rows of this tile
        #pragma unroll
        for (int n = 0; n < 3; ++n) {
            const int col = 16 * n + (int)lrow;
            if (col < 36) {
                #pragma unroll
                for (int i = 0; i < 4; ++i)
                    st_bf16(&sOUT[(Rb + 4 * lkg + i) * 88 + col * 2],
                            acc2[n][i]);
            }
        }
    }

    // ---- part losses, minimal live set: on-demand loads ----
    const float* cp = cin + (size_t)(blockIdx.x * NT + t) * 36;
    float sp[5], np[5];
    {   // head (0,14,15); gt mixes x[:,15,0] and c[:,15,1] (faithful)
        unsigned w0  = *(const unsigned*)&sOUT[t * 88 + 0];
        unsigned w28 = *(const unsigned*)&sOUT[t * 88 + 56];
        unsigned w30 = *(const unsigned*)&sOUT[t * 88 + 60];
        float o0x = __uint_as_float(w0 << 16),  o0y = __uint_as_float(w0 & 0xFFFF0000u);
        float o28 = __uint_as_float(w28 << 16), o29 = __uint_as_float(w28 & 0xFFFF0000u);
        float o30 = __uint_as_float(w30 << 16), o31 = __uint_as_float(w30 & 0xFFFF0000u);
        float2 c0  = *(const float2*)(cp + 0);
        float2 c28 = *(const float2*)(cp + 28);
        float2 c30 = *(const float2*)(cp + 30);
        float dxa = o0x - o28, dya = o0y - o29;
        float dxb = o0x - o30, dyb = o0y - o31;
        float pred = 0.5f * (sqrtf(dxa*dxa + dya*dya) + sqrtf(dxb*dxb + dyb*dyb));
        float cxa = c0.x - c28.x, cya = c0.y - c28.y;
        float gxa = c0.x - o30,   gya = c0.y - c30.y;
        float gt = 0.5f * (sqrtf(cxa*cxa + cya*cya) + sqrtf(gxa*gxa + gya*gya));
        float vf = (c0.x != -1.f && c28.x != -1.f && c30.x != -1.f) ? 1.f : 0.f;
        float e = pred - gt;
        sp[0] = e * e * vf; np[0] = vf;
    }
    #pragma unroll
    for (int p = 0; p < 4; ++p) {
        const int a = 2 + 3 * p;   // b=a+1, cc=a+2
        unsigned wA = *(const unsigned*)&sOUT[t * 88 + 4 * a + 0];
        unsigned wB = *(const unsigned*)&sOUT[t * 88 + 4 * a + 4];
        unsigned wC = *(const unsigned*)&sOUT[t * 88 + 4 * a + 8];
        float oax = __uint_as_float(wA << 16), oay = __uint_as_float(wA & 0xFFFF0000u);
        float obx = __uint_as_float(wB << 16), oby = __uint_as_float(wB & 0xFFFF0000u);
        float ocx = __uint_as_float(wC << 16), ocy = __uint_as_float(wC & 0xFFFF0000u);
        float2 ca = *(const float2*)(cp + 2 * a);
        float2 cb = *(const float2*)(cp + 2 * a + 2);
        float2 cc2 = *(const float2*)(cp + 2 * a + 4);
        float dxa = oax - obx, dya = oay - oby;
        float dxb = obx - ocx, dyb = oby - ocy;
        float pred = 0.5f * (sqrtf(dxa*dxa + dya*dya) + sqrtf(dxb*dxb + dyb*dyb));
        float cxa = ca.x - cb.x, cya = ca.y - cb.y;
        float gxa = cb.x - ocx,  gya = cb.y - cc2.y;
        float gt = 0.5f * (sqrtf(cxa*cxa + cya*cya) + sqrtf(gxa*gxa + gya*gya));
        float vf = (ca.x != -1.f && cb.x != -1.f && cc2.x != -1.f) ? 1.f : 0.f;
        float e = pred - gt;
        sp[p + 1] = e * e * vf; np[p + 1] = vf;
    }

    __syncthreads();   // all waves' out-rows complete

    // ---- coalesced x store + miss store + elementwise kp-loss ----
    const size_t blkBase = (size_t)blockIdx.x * (NT * 36);
    const float4* cin4 = (const float4*)(cin + blkBase);
    const int4*   tm4  = (const int4*)(tmask + blkBase);
    float4*       x4   = (float4*)(xout + blkBase);
    float*        mo   = missout + blkBase;

    float s1 = 0.f, s2 = 0.f;
    #pragma unroll
    for (int i = 0; i < 9; ++i) {
        int g4 = i * NT + t;
        unsigned g = 4u * (unsigned)g4;
        unsigned row = g / 36u;
        unsigned col = g - row * 36u;          // col % 4 == 0 -> 8B aligned
        uint2 w = *(const uint2*)&sOUT[row * 88u + col * 2u];
        float4 xv;
        xv.x = __uint_as_float(w.x << 16);
        xv.y = __uint_as_float(w.x & 0xFFFF0000u);
        xv.z = __uint_as_float(w.y << 16);
        xv.w = __uint_as_float(w.y & 0xFFFF0000u);
        float4 cv = cin4[g4];
        int4   mv = tm4[g4];
        x4[g4] = xv;
        mo[g + 0] = (cv.x != -1.f) ? 1.f : 0.f;
        mo[g + 1] = (cv.y != -1.f) ? 1.f : 0.f;
        mo[g + 2] = (cv.z != -1.f) ? 1.f : 0.f;
        mo[g + 3] = (cv.w != -1.f) ? 1.f : 0.f;
        float m0 = (float)mv.x, m1_ = (float)mv.y, m2_ = (float)mv.z, m3_ = (float)mv.w;
        float d0 = xv.x - cv.x, d1 = xv.y - cv.y, d2 = xv.z - cv.z, d3 = xv.w - cv.w;
        s1 += d0*d0*m0 + d1*d1*m1_ + d2*d2*m2_ + d3*d3*m3_;
        s2 += m0 + m1_ + m2_ + m3_;
    }

    // ---- block reduction of 12 scalars (scratch = dead sT1 region) ----
    float rv[12] = { s1, s2, sp[0], np[0], sp[1], np[1],
                     sp[2], np[2], sp[3], np[3], sp[4], np[4] };
    #pragma unroll
    for (int v = 0; v < 12; ++v) {
        #pragma unroll
        for (int off = 32; off > 0; off >>= 1)
            rv[v] += __shfl_down(rv[v], off, 64);
    }
    if (lane == 0) {
        float* sw = (float*)(sT1 + wave * (16 * 144));
        #pragma unroll
        for (int v = 0; v < 12; ++v) sw[v] = rv[v];
    }
    __syncthreads();
    if (t < 12) {
        float s = 0.f;
        #pragma unroll
        for (int w = 0; w < 4; ++w) s += ((const float*)(sT1 + w * (16 * 144)))[t];
        partials[blockIdx.x * 12 + t] = s;
    }
}

__global__ __launch_bounds__(256) void kp_fin(const float* __restrict__ partials,
                                              float* __restrict__ total_out)
{
    __shared__ float sred[4][12];
    const int t = threadIdx.x;
    float rv[12];
    #pragma unroll
    for (int v = 0; v < 12; ++v) rv[v] = 0.f;
    for (int b = t; b < NB; b += 256) {
        #pragma unroll
        for (int v = 0; v < 12; ++v) rv[v] += partials[b * 12 + v];
    }
    #pragma unroll
    for (int v = 0; v < 12; ++v) {
        #pragma unroll
        for (int off = 32; off > 0; off >>= 1)
            rv[v] += __shfl_down(rv[v], off, 64);
    }
    const int wave = t >> 6, lane = t & 63;
    if (lane == 0) {
        #pragma unroll
        for (int v = 0; v < 12; ++v) sred[wave][v] = rv[v];
    }
    __syncthreads();
    if (t == 0) {
        float acc[12];
        #pragma unroll
        for (int v = 0; v < 12; ++v)
            acc[v] = sred[0][v] + sred[1][v] + sred[2][v] + sred[3][v];
        float total = acc[0] / acc[1];
        #pragma unroll
        for (int p = 0; p < 5; ++p) {
            float s = acc[2 + 2 * p], n = acc[3 + 2 * p];
            total += (n > 0.f) ? (s / fmaxf(n, 1.f)) : 0.f;
        }
        total_out[0] = total;
    }
}

extern "C" void kernel_launch(void* const* d_in, const int* in_sizes, int n_in,
                              void* d_out, int out_size, void* d_ws, size_t ws_size,
                              hipStream_t stream)
{
    const float* cin   = (const float*)d_in[0];
    const int*   tmask = (const int*)  d_in[1];
    const float* w1  = (const float*)d_in[2];
    const float* b1  = (const float*)d_in[3];
    const float* g1  = (const float*)d_in[4];
    const float* bt1 = (const float*)d_in[5];
    const float* m1  = (const float*)d_in[6];
    const float* v1  = (const float*)d_in[7];
    const float* w2  = (const float*)d_in[8];
    const float* b2  = (const float*)d_in[9];
    const float* g2  = (const float*)d_in[10];
    const float* bt2 = (const float*)d_in[11];
    const float* m2  = (const float*)d_in[12];
    const float* v2  = (const float*)d_in[13];
    const float* w3  = (const float*)d_in[14];
    const float* b3  = (const float*)d_in[15];
    const float* g3  = (const float*)d_in[16];
    const float* bt3 = (const float*)d_in[17];
    const float* m3  = (const float*)d_in[18];
    const float* v3  = (const float*)d_in[19];
    const float* fw1 = (const float*)d_in[20];
    const float* fb1 = (const float*)d_in[21];
    const float* fw2 = (const float*)d_in[22];
    const float* fb2 = (const float*)d_in[23];

    float* xout     = (float*)d_out;                       // [B,36]
    float* total    = (float*)d_out + (size_t)BTOT * 36;   // scalar
    float* missout  = total + 1;                           // [B,36] as f32 0/1

    float* wsB      = (float*)d_ws;
    short* frags    = (short*)((char*)d_ws + FRAGS_BYTE);
    float* partials = (float*)((char*)d_ws + PART_BYTE);   // [NB,12]

    kp_setup<<<8, 256, 0, stream>>>(
        w1, b1, g1, bt1, m1, v1,
        w2, b2, g2, bt2, m2, v2,
        w3, b3, g3, bt3, m3, v3,
        fw1, fb1, fw2, fb2, wsB, frags);

    kp_main<<<NB, NT, 0, stream>>>(cin, tmask, wsB, frags,
        xout, missout, partials);

    kp_fin<<<1, 256, 0, stream>>>(partials, total);
}

// Round 15
// 55.591 us; speedup vs baseline: 1.4184x; 1.0248x over previous
//
#include <hip/hip_runtime.h>
#include <hip/hip_bf16.h>

#define NB   1024
#define NT   256
#define BTOT 262144   // NB*NT == B

typedef __attribute__((ext_vector_type(8))) short short8;
typedef __attribute__((ext_vector_type(4))) float f32x4;

__device__ __forceinline__ float relu_(float x) { return fmaxf(x, 0.0f); }

// setup-kernel-only (portable RNE)
__device__ __forceinline__ short f2bf(float x) {
    unsigned u = __float_as_uint(x);
    return (short)((u + 0x7FFFu + ((u >> 16) & 1u)) >> 16);
}
__device__ __forceinline__ unsigned pk2bf(float a, float b) {
    return ((unsigned)(unsigned short)f2bf(a)) |
           (((unsigned)(unsigned short)f2bf(b)) << 16);
}

// hot-path conversions: native casts -> HW v_cvt_pk_bf16_f32
__device__ __forceinline__ unsigned pkbf(float a, float b) {
    __hip_bfloat162 h = __float22bfloat162_rn(make_float2(a, b));
    return *(unsigned*)&h;
}
__device__ __forceinline__ void st_bf16(unsigned char* p, float x) {
    *(__hip_bfloat16*)p = __float2bfloat16(x);
}
__device__ __forceinline__ short8 pack8(float a0,float a1,float a2,float a3,
                                        float a4,float a5,float a6,float a7) {
    uint4 v = make_uint4(pkbf(a0,a1), pkbf(a2,a3), pkbf(a4,a5), pkbf(a6,a7));
    return *(short8*)&v;
}

// d_ws byte map:
//  0    : (reserved) | A0 packed bf16 pairs at dword 160
//  768  : 46 B-fragments x 512 shorts (bf16); K-axes PHYSICALLY PERMUTED to
//         writer-thread-contiguous LDS slot order (see per-frag maps below)
//  47872: partials [NB*12] f32
#define A0_DW    160
#define FRAGS_BYTE 768
#define PART_BYTE 47872
#define NFRAG 46

__global__ __launch_bounds__(256) void kp_setup(
    const float* __restrict__ w1, const float* __restrict__ b1,
    const float* __restrict__ g1, const float* __restrict__ bt1,
    const float* __restrict__ m1, const float* __restrict__ v1,
    const float* __restrict__ w2, const float* __restrict__ b2,
    const float* __restrict__ g2, const float* __restrict__ bt2,
    const float* __restrict__ m2, const float* __restrict__ v2,
    const float* __restrict__ w3, const float* __restrict__ b3,
    const float* __restrict__ g3, const float* __restrict__ bt3,
    const float* __restrict__ m3, const float* __restrict__ v3,
    const float* __restrict__ fw1, const float* __restrict__ fb1,
    const float* __restrict__ fw2, const float* __restrict__ fb2,
    float* __restrict__ wsB, short* __restrict__ frags)
{
    __shared__ float w1f[180], b1f[10], a0f[10];
    __shared__ float w2f[400], b2f[20];
    __shared__ float w3f[1200], b3f[30];
    const int t = threadIdx.x;

    if (t < 10) {
        float s = g1[t] * rsqrtf(v1[t] + 1e-5f);
        float bb = (b1[t] - m1[t]) * s + bt1[t];
        b1f[t] = bb; a0f[t] = relu_(bb);
        for (int i = 0; i < 18; ++i) w1f[t * 18 + i] = w1[t * 18 + i] * s;
    } else if (t >= 64 && t < 84) {
        int o = t - 64;
        float s = g2[o] * rsqrtf(v2[o] + 1e-5f);
        b2f[o] = (b2[o] - m2[o]) * s + bt2[o];
        for (int i = 0; i < 20; ++i) w2f[o * 20 + i] = w2[o * 20 + i] * s;
    } else if (t >= 128 && t < 158) {
        int o = t - 128;
        float s = g3[o] * rsqrtf(v3[o] + 1e-5f);
        b3f[o] = (b3[o] - m3[o]) * s + bt3[o];
        for (int i = 0; i < 40; ++i) w3f[o * 40 + i] = w3[o * 40 + i] * s;
    }
    __syncthreads();

    if (blockIdx.x == 0 && t < 5)
        ((unsigned*)wsB)[A0_DW + t] = pk2bf(a0f[2 * t], a0f[2 * t + 1]);

    for (int e = blockIdx.x * 256 + t; e < NFRAG * 512; e += gridDim.x * 256) {
        int frag = e >> 9, l = (e >> 3) & 63, j = e & 7;
        float val = 0.f;
        if (frag < 4) {                       // conv1: logical K (unchanged), N=20
            int p = frag, nt = p >> 1, kt = p & 1;
            int k = kt * 32 + (l >> 4) * 8 + j, n = nt * 16 + (l & 15);
            if (n < 20) {
                int o = n % 10, pp = n / 10;
                if (k < 36) { int i = k >> 1, s = k & 1; if (s == pp) val = w1f[o * 18 + i]; }
                else if (k == 36) val = b1f[o];
            }
        } else if (frag < 12) {               // conv2: a1 PHYSICAL slots
            // kp<32: slot 2r+s -> a1-logical (s==0 ? 10+r : 26+r, r<4)
            // kp 32..41: A0 (logical 0..9); 42..51: A0 (logical 30..39); 52: bias
            int p = frag - 4, nt_ = p >> 1, kt = p & 1;
            int kp = kt * 32 + (l >> 4) * 8 + j, n = nt_ * 16 + (l & 15);
            if (n < 60) {
                int lk = -1;
                if (kp < 32) { int s = kp & 1, r = kp >> 1;
                               lk = (s == 0) ? 10 + r : (r < 4 ? 26 + r : -1); }
                else if (kp < 42) lk = kp - 32;
                else if (kp < 52) lk = 30 + (kp - 42);
                else if (kp == 52) lk = 40;
                if (lk >= 0) {
                    int q = n / 20, o = n % 20;
                    if (lk < 40) { int pp = lk / 10, i = lk % 10, d = pp - q;
                                   if (d == 0 || d == 1) val = w2f[o * 20 + i * 2 + d]; }
                    else val = b2f[o];
                }
            }
        } else if (frag < 20) {               // conv3: a2 PHYSICAL p=lrow*4+nt
            int p = frag - 12, nt_ = p >> 1, kt = p & 1;
            int kp = kt * 32 + (l >> 4) * 8 + j, n = nt_ * 16 + (l & 15);
            if (n < 60) {
                int n2 = 16 * (kp & 3) + (kp >> 2);
                int q = n / 30, o = n % 30;
                if (n2 < 60) { int pp = n2 / 20, i = n2 % 20, d = pp - q;
                               if (d == 0 || d == 1) val = w3f[o * 40 + i * 2 + d]; }
                else if (n2 == 60) val = b3f[o];
            }
        } else if (frag < 34) {               // fc1: f PHYSICAL p=lrow*4+nt
            int p = frag - 20, n7 = p >> 1, kt = p & 1;
            int kp = kt * 32 + (l >> 4) * 8 + j, col = n7 * 16 + (l & 15);
            if (col < 100) {
                int n3 = 16 * (kp & 3) + (kp >> 2);
                if (n3 < 60) { int kf = 2 * (n3 % 30) + (n3 / 30);
                               val = fw1[col * 60 + kf]; }
                else if (n3 == 60) val = fb1[col];
            }
        } else {                              // fc2: z PHYSICAL p=lrow*4+nn (per half)
            int p = frag - 34, n3_ = p >> 2, kt = p & 3;
            int kp = kt * 32 + (l >> 4) * 8 + j, col = n3_ * 16 + (l & 15);
            if (col < 36) {
                int jj = 64 * (kp >> 6) + 16 * ((kp & 63) & 3) + ((kp & 63) >> 2);
                if (jj < 100) val = fw2[col * 100 + jj];
                else if (jj == 100) val = fb2[col];
            }
        }
        frags[e] = f2bf(val);
    }
}

__global__ __launch_bounds__(NT) void kp_main(
    const float* __restrict__ cin, const int* __restrict__ tmask,
    const float* __restrict__ wsB, const short* __restrict__ frags,
    float* __restrict__ xout, float* __restrict__ missout,
    float* __restrict__ partials)
{
    // 40960 B total = exactly 4 blocks/CU (LDS-wise)
    __shared__ __align__(16) unsigned char sOUT[NT * 88];       // out rows, bf16
    __shared__ __align__(16) unsigned char sT1[4 * 16 * 144];   // a1 tiles (per-wave)
    __shared__ __align__(16) unsigned char sT2[4 * 16 * 144];   // a2/f/z tiles

    const int t = threadIdx.x;
    const int lane = t & 63, wave = t >> 6;
    const unsigned lrow = (unsigned)(lane & 15);
    const unsigned lkg  = (unsigned)(lane >> 4);
    const unsigned wbase = (unsigned)(t & ~63);
    const short8* frg = (const short8*)frags;

    unsigned char* T1 = sT1 + wave * (16 * 144);
    unsigned char* T2 = sT2 + wave * (16 * 144);

    // ---- one-time: T1 constant region (physical slots 32..63, bytes 64..127)
    //   32..41=A0, 42..51=A0, 52=1.0(bias), 53..63=0
    {
        const unsigned* a0p = (const unsigned*)wsB + A0_DW;
        uint4 A0q = *(const uint4*)a0p;
        unsigned A0e = a0p[4];
        if (lane < 16) {
            unsigned char* b = &T1[(unsigned)lane * 144 + 64];
            *(uint4*)(b +  0) = A0q;
            *(uint4*)(b + 16) = make_uint4(A0e, A0q.x, A0q.y, A0q.z);
            *(uint4*)(b + 32) = make_uint4(A0q.w, A0e, 0x00003F80u, 0u);
            *(uint4*)(b + 48) = make_uint4(0u, 0u, 0u, 0u);
        }
    }

    #pragma unroll 1
    for (int m = 0; m < 4; ++m) {
        const unsigned Rb = wbase + 16u * (unsigned)m;

        // ---- conv1 A-frags straight from global ----
        const float* crow = cin + (size_t)(blockIdx.x * NT + Rb + lrow) * 36;
        float4 qa = *(const float4*)(crow + 8 * lkg);
        float4 qb = *(const float4*)(crow + 8 * lkg + 4);
        float4 qc = *(const float4*)(crow + 32);
        short8 Aa = pack8(qa.x, qa.y, qa.z, qa.w, qb.x, qb.y, qb.z, qb.w);
        float sf = (lkg == 0u) ? 1.f : 0.f;
        short8 Ab = pack8(qc.x * sf, qc.y * sf, qc.z * sf, qc.w * sf, sf, 0.f, 0.f, 0.f);

        // ---- conv1 -> a1 (T1 physical slots 2*lrow, 2*lrow+1; 1 b32/row) ----
        {
            f32x4 D1[2];
            #pragma unroll
            for (int nt = 0; nt < 2; ++nt) {
                D1[nt] = (f32x4){0.f, 0.f, 0.f, 0.f};
                D1[nt] = __builtin_amdgcn_mfma_f32_16x16x32_bf16(Aa, frg[(nt * 2 + 0) * 64 + lane], D1[nt], 0, 0, 0);
                D1[nt] = __builtin_amdgcn_mfma_f32_16x16x32_bf16(Ab, frg[(nt * 2 + 1) * 64 + lane], D1[nt], 0, 0, 0);
            }
            // D1[1] is exactly 0 for lrow>=4 (B cols >=20 are zero) -> no select
            #pragma unroll
            for (int i = 0; i < 4; ++i)
                *(unsigned*)&T1[(4 * lkg + i) * 144 + lrow * 4] =
                    pkbf(relu_(D1[0][i]), relu_(D1[1][i]));
        }

        // ---- conv2: A = a1 (K=64 phys) -> a2 (T2 physical p=lrow*4+nt; 1 b64/row)
        Aa = *(const short8*)&T1[lrow * 144 + lkg * 16u];
        Ab = *(const short8*)&T1[lrow * 144 + 64u + lkg * 16u];
        {
            f32x4 D2[4];
            #pragma unroll
            for (int nt = 0; nt < 4; ++nt) {
                D2[nt] = (f32x4){0.f, 0.f, 0.f, 0.f};
                D2[nt] = __builtin_amdgcn_mfma_f32_16x16x32_bf16(Aa, frg[(4 + nt * 2 + 0) * 64 + lane], D2[nt], 0, 0, 0);
                D2[nt] = __builtin_amdgcn_mfma_f32_16x16x32_bf16(Ab, frg[(4 + nt * 2 + 1) * 64 + lane], D2[nt], 0, 0, 0);
            }
            // slot 51 (lrow==12, nt==3) = K-bias 1.0; lrow>12,nt3 naturally 0
            #pragma unroll
            for (int i = 0; i < 4; ++i) {
                float e3 = (lrow == 12u) ? 1.0f : relu_(D2[3][i]);
                uint2 wv = make_uint2(pkbf(relu_(D2[0][i]), relu_(D2[1][i])),
                                      pkbf(relu_(D2[2][i]), e3));
                *(uint2*)&T2[(4 * lkg + i) * 144 + lrow * 8] = wv;
            }
        }

        // ---- conv3: A = a2 -> f (same physical scheme; 1 b64/row) ----
        Aa = *(const short8*)&T2[lrow * 144 + lkg * 16u];
        Ab = *(const short8*)&T2[lrow * 144 + 64u + lkg * 16u];
        {
            f32x4 D3[4];
            #pragma unroll
            for (int nt = 0; nt < 4; ++nt) {
                D3[nt] = (f32x4){0.f, 0.f, 0.f, 0.f};
                D3[nt] = __builtin_amdgcn_mfma_f32_16x16x32_bf16(Aa, frg[(12 + nt * 2 + 0) * 64 + lane], D3[nt], 0, 0, 0);
                D3[nt] = __builtin_amdgcn_mfma_f32_16x16x32_bf16(Ab, frg[(12 + nt * 2 + 1) * 64 + lane], D3[nt], 0, 0, 0);
            }
            #pragma unroll
            for (int i = 0; i < 4; ++i) {
                float e3 = (lrow == 12u) ? 1.0f : relu_(D3[3][i]);
                uint2 wv = make_uint2(pkbf(relu_(D3[0][i]), relu_(D3[1][i])),
                                      pkbf(relu_(D3[2][i]), e3));
                *(uint2*)&T2[(4 * lkg + i) * 144 + lrow * 8] = wv;
            }
        }

        // ---- fc1 + fc2 (z physical p=lrow*4+nn per 64-slot half; b32 pairs) ----
        short8 Fa = *(const short8*)&T2[lrow * 144 + lkg * 16u];
        short8 Fb = *(const short8*)&T2[lrow * 144 + 64u + lkg * 16u];
        f32x4 acc2[3];
        #pragma unroll
        for (int n = 0; n < 3; ++n) acc2[n] = (f32x4){0.f, 0.f, 0.f, 0.f};

        #pragma unroll
        for (int h = 0; h < 2; ++h) {
            #pragma unroll
            for (int pr = 0; pr < 2; ++pr) {
                const int n0 = 4 * h + 2 * pr;   // <= 6 always
                const int n1 = n0 + 1;           // == 7 only at h=1,pr=1
                f32x4 va = (f32x4){0.f, 0.f, 0.f, 0.f};
                f32x4 vb = (f32x4){0.f, 0.f, 0.f, 0.f};
                va = __builtin_amdgcn_mfma_f32_16x16x32_bf16(Fa, frg[(20 + n0 * 2 + 0) * 64 + lane], va, 0, 0, 0);
                va = __builtin_amdgcn_mfma_f32_16x16x32_bf16(Fb, frg[(20 + n0 * 2 + 1) * 64 + lane], va, 0, 0, 0);
                if (n1 < 7) {
                    vb = __builtin_amdgcn_mfma_f32_16x16x32_bf16(Fa, frg[(20 + n1 * 2 + 0) * 64 + lane], vb, 0, 0, 0);
                    vb = __builtin_amdgcn_mfma_f32_16x16x32_bf16(Fb, frg[(20 + n1 * 2 + 1) * 64 + lane], vb, 0, 0, 0);
                }
                #pragma unroll
                for (int i = 0; i < 4; ++i) {
                    float z0 = relu_(va[i]);
                    if (h == 1 && pr == 1 && lrow == 4u) z0 = 1.0f;  // z[100]=bias
                    float z1 = (n1 < 7) ? relu_(vb[i]) : 0.f;
                    *(unsigned*)&T2[(4 * lkg + i) * 144 + lrow * 8 + 4 * pr] =
                        pkbf(z0, z1);
                }
            }
            #pragma unroll
            for (int q = 0; q < 2; ++q) {
                const int kt = 2 * h + q;
                short8 Az = *(const short8*)&T2[lrow * 144 + (unsigned)(q * 64) + lkg * 16u];
                #pragma unroll
                for (int n = 0; n < 3; ++n)
                    acc2[n] = __builtin_amdgcn_mfma_f32_16x16x32_bf16(Az, frg[(34 + n * 4 + kt) * 64 + lane], acc2[n], 0, 0, 0);
            }
        }

        // out (bf16) -> sOUT rows of this tile
        #pragma unroll
        for (int n = 0; n < 3; ++n) {
            const int col = 16 * n + (int)lrow;
            if (col < 36) {
                #pragma unroll
                for (int i = 0; i < 4; ++i)
                    st_bf16(&sOUT[(Rb + 4 * lkg + i) * 88 + col * 2],
                            acc2[n][i]);
            }
        }
    }

    // ---- part losses, minimal live set: on-demand loads ----
    const float* cp = cin + (size_t)(blockIdx.x * NT + t) * 36;
    float sp[5], np[5];
    {   // head (0,14,15); gt mixes x[:,15,0] and c[:,15,1] (faithful)
        unsigned w0  = *(const unsigned*)&sOUT[t * 88 + 0];
        unsigned w28 = *(const unsigned*)&sOUT[t * 88 + 56];
        unsigned w30 = *(const unsigned*)&sOUT[t * 88 + 60];
        float o0x = __uint_as_float(w0 << 16),  o0y = __uint_as_float(w0 & 0xFFFF0000u);
        float o28 = __uint_as_float(w28 << 16), o29 = __uint_as_float(w28 & 0xFFFF0000u);
        float o30 = __uint_as_float(w30 << 16), o31 = __uint_as_float(w30 & 0xFFFF0000u);
        float2 c0  = *(const float2*)(cp + 0);
        float2 c28 = *(const float2*)(cp + 28);
        float2 c30 = *(const float2*)(cp + 30);
        float dxa = o0x - o28, dya = o0y - o29;
        float dxb = o0x - o30, dyb = o0y - o31;
        float pred = 0.5f * (sqrtf(dxa*dxa + dya*dya) + sqrtf(dxb*dxb + dyb*dyb));
        float cxa = c0.x - c28.x, cya = c0.y - c28.y;
        float gxa = c0.x - o30,   gya = c0.y - c30.y;
        float gt = 0.5f * (sqrtf(cxa*cxa + cya*cya) + sqrtf(gxa*gxa + gya*gya));
        float vf = (c0.x != -1.f && c28.x != -1.f && c30.x != -1.f) ? 1.f : 0.f;
        float e = pred - gt;
        sp[0] = e * e * vf; np[0] = vf;
    }
    #pragma unroll
    for (int p = 0; p < 4; ++p) {
        const int a = 2 + 3 * p;   // b=a+1, cc=a+2
        unsigned wA = *(const unsigned*)&sOUT[t * 88 + 4 * a + 0];
        unsigned wB = *(const unsigned*)&sOUT[t * 88 + 4 * a + 4];
        unsigned wC = *(const unsigned*)&sOUT[t * 88 + 4 * a + 8];
        float oax = __uint_as_float(wA << 16), oay = __uint_as_float(wA & 0xFFFF0000u);
        float obx = __uint_as_float(wB << 16), oby = __uint_as_float(wB & 0xFFFF0000u);
        float ocx = __uint_as_float(wC << 16), ocy = __uint_as_float(wC & 0xFFFF0000u);
        float2 ca = *(const float2*)(cp + 2 * a);
        float2 cb = *(const float2*)(cp + 2 * a + 2);
        float2 cc2 = *(const float2*)(cp + 2 * a + 4);
        float dxa = oax - obx, dya = oay - oby;
        float dxb = obx - ocx, dyb = oby - ocy;
        float pred = 0.5f * (sqrtf(dxa*dxa + dya*dya) + sqrtf(dxb*dxb + dyb*dyb));
        float cxa = ca.x - cb.x, cya = ca.y - cb.y;
        float gxa = cb.x - ocx,  gya = cb.y - cc2.y;
        float gt = 0.5f * (sqrtf(cxa*cxa + cya*cya) + sqrtf(gxa*gxa + gya*gya));
        float vf = (ca.x != -1.f && cb.x != -1.f && cc2.x != -1.f) ? 1.f : 0.f;
        float e = pred - gt;
        sp[p + 1] = e * e * vf; np[p + 1] = vf;
    }

    __syncthreads();   // all waves' out-rows complete

    // ---- coalesced x store + miss store + elementwise kp-loss ----
    const size_t blkBase = (size_t)blockIdx.x * (NT * 36);
    const float4* cin4 = (const float4*)(cin + blkBase);
    const int4*   tm4  = (const int4*)(tmask + blkBase);
    float4*       x4   = (float4*)(xout + blkBase);
    float*        mo   = missout + blkBase;

    float s1 = 0.f, s2 = 0.f;
    #pragma unroll
    for (int i = 0; i < 9; ++i) {
        int g4 = i * NT + t;
        unsigned g = 4u * (unsigned)g4;
        unsigned row = g / 36u;
        unsigned col = g - row * 36u;          // col % 4 == 0 -> 8B aligned
        uint2 w = *(const uint2*)&sOUT[row * 88u + col * 2u];
        float4 xv;
        xv.x = __uint_as_float(w.x << 16);
        xv.y = __uint_as_float(w.x & 0xFFFF0000u);
        xv.z = __uint_as_float(w.y << 16);
        xv.w = __uint_as_float(w.y & 0xFFFF0000u);
        float4 cv = cin4[g4];
        int4   mv = tm4[g4];
        x4[g4] = xv;
        mo[g + 0] = (cv.x != -1.f) ? 1.f : 0.f;
        mo[g + 1] = (cv.y != -1.f) ? 1.f : 0.f;
        mo[g + 2] = (cv.z != -1.f) ? 1.f : 0.f;
        mo[g + 3] = (cv.w != -1.f) ? 1.f : 0.f;
        float m0 = (float)mv.x, m1_ = (float)mv.y, m2_ = (float)mv.z, m3_ = (float)mv.w;
        float d0 = xv.x - cv.x, d1 = xv.y - cv.y, d2 = xv.z - cv.z, d3 = xv.w - cv.w;
        s1 += d0*d0*m0 + d1*d1*m1_ + d2*d2*m2_ + d3*d3*m3_;
        s2 += m0 + m1_ + m2_ + m3_;
    }

    // ---- block reduction of 12 scalars (scratch = dead sT1 region) ----
    float rv[12] = { s1, s2, sp[0], np[0], sp[1], np[1],
                     sp[2], np[2], sp[3], np[3], sp[4], np[4] };
    #pragma unroll
    for (int v = 0; v < 12; ++v) {
        #pragma unroll
        for (int off = 32; off > 0; off >>= 1)
            rv[v] += __shfl_down(rv[v], off, 64);
    }
    if (lane == 0) {
        float* sw = (float*)(sT1 + wave * (16 * 144));
        #pragma unroll
        for (int v = 0; v < 12; ++v) sw[v] = rv[v];
    }
    __syncthreads();
    if (t < 12) {
        float s = 0.f;
        #pragma unroll
        for (int w = 0; w < 4; ++w) s += ((const float*)(sT1 + w * (16 * 144)))[t];
        partials[blockIdx.x * 12 + t] = s;
    }
}

__global__ __launch_bounds__(256) void kp_fin(const float* __restrict__ partials,
                                              float* __restrict__ total_out)
{
    __shared__ float sred[4][12];
    const int t = threadIdx.x;
    float rv[12];
    #pragma unroll
    for (int v = 0; v < 12; ++v) rv[v] = 0.f;
    for (int b = t; b < NB; b += 256) {
        #pragma unroll
        for (int v = 0; v < 12; ++v) rv[v] += partials[b * 12 + v];
    }
    #pragma unroll
    for (int v = 0; v < 12; ++v) {
        #pragma unroll
        for (int off = 32; off > 0; off >>= 1)
            rv[v] += __shfl_down(rv[v], off, 64);
    }
    const int wave = t >> 6, lane = t & 63;
    if (lane == 0) {
        #pragma unroll
        for (int v = 0; v < 12; ++v) sred[wave][v] = rv[v];
    }
    __syncthreads();
    if (t == 0) {
        float acc[12];
        #pragma unroll
        for (int v = 0; v < 12; ++v)
            acc[v] = sred[0][v] + sred[1][v] + sred[2][v] + sred[3][v];
        float total = acc[0] / acc[1];
        #pragma unroll
        for (int p = 0; p < 5; ++p) {
            float s = acc[2 + 2 * p], n = acc[3 + 2 * p];
            total += (n > 0.f) ? (s / fmaxf(n, 1.f)) : 0.f;
        }
        total_out[0] = total;
    }
}

extern "C" void kernel_launch(void* const* d_in, const int* in_sizes, int n_in,
                              void* d_out, int out_size, void* d_ws, size_t ws_size,
                              hipStream_t stream)
{
    const float* cin   = (const float*)d_in[0];
    const int*   tmask = (const int*)  d_in[1];
    const float* w1  = (const float*)d_in[2];
    const float* b1  = (const float*)d_in[3];
    const float* g1  = (const float*)d_in[4];
    const float* bt1 = (const float*)d_in[5];
    const float* m1  = (const float*)d_in[6];
    const float* v1  = (const float*)d_in[7];
    const float* w2  = (const float*)d_in[8];
    const float* b2  = (const float*)d_in[9];
    const float* g2  = (const float*)d_in[10];
    const float* bt2 = (const float*)d_in[11];
    const float* m2  = (const float*)d_in[12];
    const float* v2  = (const float*)d_in[13];
    const float* w3  = (const float*)d_in[14];
    const float* b3  = (const float*)d_in[15];
    const float* g3  = (const float*)d_in[16];
    const float* bt3 = (const float*)d_in[17];
    const float* m3  = (const float*)d_in[18];
    const float* v3  = (const float*)d_in[19];
    const float* fw1 = (const float*)d_in[20];
    const float* fb1 = (const float*)d_in[21];
    const float* fw2 = (const float*)d_in[22];
    const float* fb2 = (const float*)d_in[23];

    float* xout     = (float*)d_out;                       // [B,36]
    float* total    = (float*)d_out + (size_t)BTOT * 36;   // scalar
    float* missout  = total + 1;                           // [B,36] as f32 0/1

    float* wsB      = (float*)d_ws;
    short* frags    = (short*)((char*)d_ws + FRAGS_BYTE);
    float* partials = (float*)((char*)d_ws + PART_BYTE);   // [NB,12]

    kp_setup<<<8, 256, 0, stream>>>(
        w1, b1, g1, bt1, m1, v1,
        w2, b2, g2, bt2, m2, v2,
        w3, b3, g3, bt3, m3, v3,
        fw1, fb1, fw2, fb2, wsB, frags);

    kp_main<<<NB, NT, 0, stream>>>(cin, tmask, wsB, frags,
        xout, missout, partials);

    kp_fin<<<1, 256, 0, stream>>>(partials, total);
}